// Round 2
// baseline (2729.131 us; speedup 1.0000x reference)
//
#include <hip/hip_runtime.h>
#include <hip/hip_bf16.h>
#include <math.h>

#define BB 32
#define TT 2048
#define DM 512
#define SS 64
#define BT (BB*TT)
#define NSTEPS 4
#define TOPK_N 8
typedef __hip_bfloat16 bf16;

static __device__ __forceinline__ float wave_reduce_sum(float v){
  #pragma unroll
  for (int off=32; off; off>>=1) v += __shfl_down(v, off);
  return v;
}

// tokens(bf16) = LN(token_emb[ids] + pos_emb[t]) ; one block per (b,t) row
__global__ __launch_bounds__(256) void embed_ln_k(const int* __restrict__ ids,
    const float* __restrict__ temb, const float* __restrict__ pemb,
    const float* __restrict__ g, const float* __restrict__ be, bf16* __restrict__ out){
  int row = blockIdx.x;
  int t = row & (TT-1);
  int id = ids[row];
  int d = threadIdx.x;
  const float* te = temb + (size_t)id*DM;
  const float* pe = pemb + (size_t)t*DM;
  float x0 = te[d] + pe[d];
  float x1 = te[d+256] + pe[d+256];
  float s1 = x0+x1, s2 = x0*x0 + x1*x1;
  s1 = wave_reduce_sum(s1); s2 = wave_reduce_sum(s2);
  __shared__ float r1[4], r2[4];
  int lane = d & 63, w = d>>6;
  if (lane==0){ r1[w]=s1; r2[w]=s2; }
  __syncthreads();
  float S1 = r1[0]+r1[1]+r1[2]+r1[3];
  float S2 = r2[0]+r2[1]+r2[2]+r2[3];
  float mu = S1 * (1.f/DM);
  float var = S2*(1.f/DM) - mu*mu;
  float rs = rsqrtf(var + 1e-5f);
  bf16* orow = out + (size_t)row*DM;
  orow[d]     = __float2bfloat16((x0-mu)*rs*g[d] + be[d]);
  orow[d+256] = __float2bfloat16((x1-mu)*rs*g[d+256] + be[d+256]);
}

// C[M x 512] = A[M x 512] @ W[512 x 512] (+ epilogue). M multiple of 64.
// EPI 0: C = acc + bias[c]
// EPI 1: C = mul / (1+exp(-(acc+bias[c])))          (sigmoid-gate epilogue)
// EPI 2: C = acc + rowscale[r]*bias[c]
template<int EPI>
__global__ __launch_bounds__(256) void gemm512_k(const float* __restrict__ A,
    const float* __restrict__ W, const float* __restrict__ bias,
    const float* __restrict__ mul, float* __restrict__ C, int M){
  __shared__ float As[64][17];
  __shared__ float Ws[16][65];
  int row0 = blockIdx.x*64, col0 = blockIdx.y*64;
  int tid = threadIdx.x, ty = tid>>4, tx = tid&15;
  float acc[4][4] = {};
  for (int k0=0; k0<DM; k0+=16){
    #pragma unroll
    for (int i=0;i<4;i++){
      int idx = tid + i*256;
      As[idx>>4][idx&15] = A[(size_t)(row0 + (idx>>4))*DM + k0 + (idx&15)];
    }
    #pragma unroll
    for (int i=0;i<4;i++){
      int idx = tid + i*256;
      Ws[idx>>6][idx&63] = W[(size_t)(k0 + (idx>>6))*DM + col0 + (idx&63)];
    }
    __syncthreads();
    #pragma unroll
    for (int kk=0;kk<16;kk++){
      float a[4], b[4];
      #pragma unroll
      for (int i=0;i<4;i++) a[i] = As[ty+16*i][kk];
      #pragma unroll
      for (int j=0;j<4;j++) b[j] = Ws[kk][tx+16*j];
      #pragma unroll
      for (int i=0;i<4;i++)
        #pragma unroll
        for (int j=0;j<4;j++) acc[i][j] += a[i]*b[j];
    }
    __syncthreads();
  }
  #pragma unroll
  for (int i=0;i<4;i++){
    int r = row0 + ty + 16*i;
    #pragma unroll
    for (int j=0;j<4;j++){
      int c = col0 + tx + 16*j;
      float v = acc[i][j];
      if (EPI==0) v += bias[c];
      if (EPI==1) v = mul[(size_t)r*DM + c] / (1.f + expf(-(v + bias[c])));
      if (EPI==2) v += mul[r]*bias[c];
      C[(size_t)r*DM + c] = v;
    }
  }
}

// P[b,d,s] = scale * sum_o qW[d,o]*kk[b,s,o]   (NT gemm, M=512 d-tile 64, N=64, K=512)
__global__ __launch_bounds__(256) void prep_k(const float* __restrict__ qW,
    const float* __restrict__ kk, float* __restrict__ P){
  int b = blockIdx.y, d0 = blockIdx.x*64;
  __shared__ float As[64][17];
  __shared__ float Bs[64][17];
  int tid=threadIdx.x, ty=tid>>4, tx=tid&15;
  float acc[4][4] = {};
  for (int k0=0;k0<DM;k0+=16){
    #pragma unroll
    for (int i=0;i<4;i++){int idx=tid+i*256; As[idx>>4][idx&15] = qW[(size_t)(d0 + (idx>>4))*DM + k0 + (idx&15)];}
    #pragma unroll
    for (int i=0;i<4;i++){int idx=tid+i*256; Bs[idx>>4][idx&15] = kk[((size_t)b*SS + (idx>>4))*DM + k0 + (idx&15)];}
    __syncthreads();
    #pragma unroll
    for (int kq=0;kq<16;kq++){
      float a[4],bv[4];
      #pragma unroll
      for (int i=0;i<4;i++) a[i]=As[ty+16*i][kq];
      #pragma unroll
      for (int j=0;j<4;j++) bv[j]=Bs[tx+16*j][kq];
      #pragma unroll
      for (int i=0;i<4;i++)
        #pragma unroll
        for (int j=0;j<4;j++) acc[i][j]+=a[i]*bv[j];
    }
    __syncthreads();
  }
  const float scale = 0.044194173824159216f;
  #pragma unroll
  for (int i=0;i<4;i++){
    int d = d0+ty+16*i;
    #pragma unroll
    for (int j=0;j<4;j++){
      int s = tx+16*j;
      P[((size_t)b*DM + d)*SS + s] = acc[i][j]*scale;
    }
  }
}

// cb[b,s] = scale * sum_o qb[o]*kk[b,s,o]
__global__ __launch_bounds__(64) void cb_k(const float* __restrict__ qb,
    const float* __restrict__ kk, float* __restrict__ cb){
  int b = blockIdx.x, s = threadIdx.x;
  const float* row = kk + ((size_t)b*SS + s)*DM;
  float acc = 0.f;
  for (int o=0;o<DM;o++) acc += qb[o]*row[o];
  cb[b*SS + s] = acc * 0.044194173824159216f;
}

// SC[b,t,s] = sum_d tok[b,t,d]*P[b,d,s] + cb[b,s]   (NN, A bf16)
__global__ __launch_bounds__(256) void scores_k(const bf16* __restrict__ tok,
    const float* __restrict__ P, const float* __restrict__ cb, float* __restrict__ SC){
  int b = blockIdx.y, t0 = blockIdx.x*64;
  __shared__ float As[64][17];
  __shared__ float Bs[16][65];
  int tid=threadIdx.x, ty=tid>>4, tx=tid&15;
  float acc[4][4] = {};
  for (int k0=0;k0<DM;k0+=16){
    #pragma unroll
    for (int i=0;i<4;i++){int idx=tid+i*256;
      As[idx>>4][idx&15] = __bfloat162float(tok[((size_t)b*TT + t0 + (idx>>4))*DM + k0 + (idx&15)]);}
    #pragma unroll
    for (int i=0;i<4;i++){int idx=tid+i*256;
      Bs[idx>>6][idx&63] = P[((size_t)b*DM + k0 + (idx>>6))*SS + (idx&63)];}
    __syncthreads();
    #pragma unroll
    for (int kq=0;kq<16;kq++){
      float a[4],bv[4];
      #pragma unroll
      for (int i=0;i<4;i++) a[i]=As[ty+16*i][kq];
      #pragma unroll
      for (int j=0;j<4;j++) bv[j]=Bs[kq][tx+16*j];
      #pragma unroll
      for (int i=0;i<4;i++)
        #pragma unroll
        for (int j=0;j<4;j++) acc[i][j]+=a[i]*bv[j];
    }
    __syncthreads();
  }
  #pragma unroll
  for (int i=0;i<4;i++){
    int t = t0+ty+16*i;
    #pragma unroll
    for (int j=0;j<4;j++){
      int s = tx+16*j;
      SC[((size_t)b*TT + t)*SS + s] = acc[i][j] + cb[b*SS + s];
    }
  }
}

// per (b,t) row: clip, top-8 (lower-index tie-break), softmax over top-8, mask. In-place.
__global__ __launch_bounds__(256) void binding_k(float* __restrict__ SC, const int* __restrict__ mask){
  int wid = (blockIdx.x*256 + threadIdx.x) >> 6;
  int lane = threadIdx.x & 63;
  float s = SC[(size_t)wid*SS + lane];
  s = fminf(fmaxf(s, -10.f), 10.f);
  float work = s;
  float topmax = 0.f;
  bool sel = false;
  #pragma unroll
  for (int it=0; it<TOPK_N; ++it){
    float v = work; int idx = lane;
    #pragma unroll
    for (int off=32; off; off>>=1){
      float ov = __shfl_xor(v, off);
      int oi = __shfl_xor(idx, off);
      if (ov > v || (ov == v && oi < idx)) { v = ov; idx = oi; }
    }
    if (it==0) topmax = v;
    if (lane == idx){ sel = true; work = -INFINITY; }
  }
  float e = sel ? expf(s - topmax) : 0.f;
  float tot = e;
  #pragma unroll
  for (int off=32; off; off>>=1) tot += __shfl_xor(tot, off);
  float m = (float)mask[wid];
  float w = (m != 0.f) ? (e / tot) : 0.f;
  SC[(size_t)wid*SS + lane] = w;
}

// column sums of binding. mode 0: slot=max(sum,1e-6), rr=sum/slot. mode 1: slot=sum.
__global__ __launch_bounds__(256) void colsum_k(const float* __restrict__ BND,
    float* __restrict__ slot, float* __restrict__ rr, int mode){
  int b = blockIdx.x;
  int s = threadIdx.x & 63, chunk = threadIdx.x >> 6;
  float sum = 0.f;
  for (int t = chunk*512; t < chunk*512+512; ++t)
    sum += BND[((size_t)b*TT + t)*SS + s];
  __shared__ float red[4][64];
  red[chunk][s] = sum;
  __syncthreads();
  if (chunk==0){
    float tot = red[0][s]+red[1][s]+red[2][s]+red[3][s];
    if (mode==0){
      float sl = fmaxf(tot, 1e-6f);
      slot[b*SS + s] = sl;
      rr[b*SS + s] = tot / sl;
    } else {
      slot[b*SS + s] = tot;
    }
  }
}

// OUT[b,s,d] = (sum_t BND[b,t,s] * tok[b,t,d]) / slot[b,s]
__global__ __launch_bounds__(256) void wt_gemm_k(const float* __restrict__ BND,
    const bf16* __restrict__ tok, const float* __restrict__ slot, float* __restrict__ OUT){
  int b = blockIdx.y, d0 = blockIdx.x*64;
  __shared__ float Bs[16][65];
  __shared__ float Vs[16][65];
  int tid=threadIdx.x, ty=tid>>4, tx=tid&15;
  float acc[4][4]={};
  for (int t0=0;t0<TT;t0+=16){
    #pragma unroll
    for (int i=0;i<4;i++){int idx=tid+i*256;
      Bs[idx>>6][idx&63] = BND[((size_t)b*TT + t0 + (idx>>6))*SS + (idx&63)];}
    #pragma unroll
    for (int i=0;i<4;i++){int idx=tid+i*256;
      Vs[idx>>6][idx&63] = __bfloat162float(tok[((size_t)b*TT + t0 + (idx>>6))*DM + d0 + (idx&63)]);}
    __syncthreads();
    #pragma unroll
    for (int kt=0;kt<16;kt++){
      float a[4],bv[4];
      #pragma unroll
      for (int i=0;i<4;i++) a[i]=Bs[kt][ty+16*i];
      #pragma unroll
      for (int j=0;j<4;j++) bv[j]=Vs[kt][tx+16*j];
      #pragma unroll
      for (int i=0;i<4;i++)
        #pragma unroll
        for (int j=0;j<4;j++) acc[i][j]+=a[i]*bv[j];
    }
    __syncthreads();
  }
  #pragma unroll
  for (int i=0;i<4;i++){
    int s = ty+16*i;
    float inv = 1.f / slot[b*SS + s];
    #pragma unroll
    for (int j=0;j<4;j++){
      int d = d0+tx+16*j;
      OUT[((size_t)b*SS + s)*DM + d] = acc[i][j]*inv;
    }
  }
}

__global__ void meminit_k(const float* __restrict__ src, float* __restrict__ mem){
  int i = blockIdx.x*256 + threadIdx.x;
  mem[i] = src[i & (SS*DM-1)];
}

// mem = LN(0.9*mem + 0.1*w3), in-place; one block per (b,s) row
__global__ __launch_bounds__(256) void mem_ln_k(float* __restrict__ mem, const float* __restrict__ w3,
    const float* __restrict__ g, const float* __restrict__ be){
  int row = blockIdx.x;
  int d = threadIdx.x;
  float* mrow = mem + (size_t)row*DM;
  const float* wrow = w3 + (size_t)row*DM;
  float x0 = 0.9f*mrow[d]     + 0.1f*wrow[d];
  float x1 = 0.9f*mrow[d+256] + 0.1f*wrow[d+256];
  float s1 = x0+x1, s2 = x0*x0 + x1*x1;
  s1 = wave_reduce_sum(s1); s2 = wave_reduce_sum(s2);
  __shared__ float r1[4], r2[4];
  int lane = d & 63, w = d>>6;
  if (lane==0){ r1[w]=s1; r2[w]=s2; }
  __syncthreads();
  float S1 = r1[0]+r1[1]+r1[2]+r1[3];
  float S2 = r2[0]+r2[1]+r2[2]+r2[3];
  float mu = S1 * (1.f/DM);
  float var = S2*(1.f/DM) - mu*mu;
  float rs = rsqrtf(var + 1e-5f);
  mrow[d]     = (x0-mu)*rs*g[d] + be[d];
  mrow[d+256] = (x1-mu)*rs*g[d+256] + be[d+256];
}

// out[b,d] = sum_t mask*tok[b,t,d]
__global__ __launch_bounds__(256) void toksum_k(const bf16* __restrict__ tok,
    const int* __restrict__ mask, float* __restrict__ out){
  int b = blockIdx.x, d = threadIdx.x;
  float s0=0, s1=0;
  for (int t=0;t<TT;++t){
    float m = (float)mask[b*TT + t];
    const bf16* row = tok + ((size_t)b*TT + t)*DM;
    s0 += m*__bfloat162float(row[d]);
    s1 += m*__bfloat162float(row[d+256]);
  }
  out[b*DM + d] = s0;
  out[b*DM + d + 256] = s1;
}

// ctx_sum = rws @ rv ; pooled = (cat(tok_sum, ctx_sum)@fuseW + denom*fuseb)/max(denom,1);
// out = pooled@clsW + clsb
__global__ __launch_bounds__(256) void final_k(const float* __restrict__ toks,
    const float* __restrict__ rws, const float* __restrict__ rv,
    const int* __restrict__ mask, const float* __restrict__ fuseW, const float* __restrict__ fuseb,
    const float* __restrict__ clsW, const float* __restrict__ clsb, float* __restrict__ out){
  int b = blockIdx.x, tid = threadIdx.x;
  __shared__ float cat[2*DM];
  __shared__ float pooled[DM];
  __shared__ float dred[4];
  float dn = 0;
  for (int t=tid; t<TT; t+=256) dn += (float)mask[b*TT+t];
  dn = wave_reduce_sum(dn);
  if ((tid&63)==0) dred[tid>>6]=dn;
  __syncthreads();
  float denom = dred[0]+dred[1]+dred[2]+dred[3];
  for (int d=tid; d<DM; d+=256){
    cat[d] = toks[b*DM + d];
    float c = 0;
    for (int s=0;s<SS;s++) c += rws[b*SS+s]*rv[((size_t)b*SS+s)*DM + d];
    cat[DM+d] = c;
  }
  __syncthreads();
  float dinv = 1.f/fmaxf(denom, 1.f);
  for (int d=tid; d<DM; d+=256){
    float acc = 0;
    for (int k=0;k<2*DM;k++) acc += cat[k]*fuseW[(size_t)k*DM + d];
    pooled[d] = (acc + denom*fuseb[d])*dinv;
  }
  __syncthreads();
  if (tid < 8){
    float acc=0;
    for (int d=0;d<DM;d++) acc += pooled[d]*clsW[d*8+tid];
    out[b*8+tid] = acc + clsb[tid];
  }
}

extern "C" void kernel_launch(void* const* d_in, const int* in_sizes, int n_in,
                              void* d_out, int out_size, void* d_ws, size_t ws_size,
                              hipStream_t stream){
  (void)in_sizes; (void)n_in; (void)out_size; (void)ws_size;
  const int*   ids   = (const int*)d_in[0];
  const int*   amask = (const int*)d_in[1];
  const float* temb  = (const float*)d_in[2];
  const float* pemb  = (const float*)d_in[3];
  const float* mem0  = (const float*)d_in[4];
  const float* qW=(const float*)d_in[5],  *qB=(const float*)d_in[6];
  const float* kW=(const float*)d_in[7],  *kB=(const float*)d_in[8];
  const float* vW=(const float*)d_in[9],  *vB=(const float*)d_in[10];
  const float* wrW=(const float*)d_in[11],*wrB=(const float*)d_in[12];
  const float* gtW=(const float*)d_in[13],*gtB=(const float*)d_in[14];
  const float* rqW=(const float*)d_in[15],*rqB=(const float*)d_in[16];
  const float* rkW=(const float*)d_in[17],*rkB=(const float*)d_in[18];
  const float* rvW=(const float*)d_in[19],*rvB=(const float*)d_in[20];
  const float* fW=(const float*)d_in[21], *fB=(const float*)d_in[22];
  const float* cW=(const float*)d_in[23], *cB=(const float*)d_in[24];
  const float* tg=(const float*)d_in[25], *tb=(const float*)d_in[26];
  const float* mg=(const float*)d_in[27], *mb=(const float*)d_in[28];

  // ---- workspace layout (105 MB total) ----
  bf16* tokens = (bf16*)d_ws;                              // BT*DM bf16 = 67.1 MB
  float* fb = (float*)((char*)d_ws + (size_t)BT*DM*sizeof(bf16));
  size_t o = 0;
  float* sc   = fb + o; o += (size_t)BT*SS;     // 16.8 MB
  float* mem  = fb + o; o += (size_t)BB*SS*DM;  // 4.2 MB
  float* kkb  = fb + o; o += (size_t)BB*SS*DM;
  float* P    = fb + o; o += (size_t)BB*DM*SS;
  float* t1   = fb + o; o += (size_t)BB*SS*DM;
  float* t2   = fb + o; o += (size_t)BB*SS*DM;
  float* cbuf = fb + o; o += (size_t)BB*SS;
  float* slot = fb + o; o += (size_t)BB*SS;
  float* rr   = fb + o; o += (size_t)BB*SS;
  float* rws  = fb + o; o += (size_t)BB*SS;
  float* tsum = fb + o; o += (size_t)BB*DM;

  embed_ln_k<<<BT, 256, 0, stream>>>(ids, temb, pemb, tg, tb, tokens);
  meminit_k<<<(BB*SS*DM)/256, 256, 0, stream>>>(mem0, mem);

  for (int step=0; step<NSTEPS; ++step){
    // kk = mem @ kW + kb
    gemm512_k<0><<<dim3(BB*SS/64, 8), 256, 0, stream>>>(mem, kW, kB, nullptr, kkb, BB*SS);
    // P_b = scale * qW @ kk_b^T ; cb = scale * qb . kk
    prep_k<<<dim3(DM/64, BB), 256, 0, stream>>>(qW, kkb, P);
    cb_k<<<BB, 64, 0, stream>>>(qB, kkb, cbuf);
    // scores = tokens @ P + cb
    scores_k<<<dim3(TT/64, BB), 256, 0, stream>>>(tokens, P, cbuf, sc);
    binding_k<<<BT/4, 256, 0, stream>>>(sc, amask);
    colsum_k<<<BB, 256, 0, stream>>>(sc, slot, rr, 0);
    // WT' = (binding^T @ tokens)/slot ; Y = WT'@vW + rr*vb ; Z = Y@wrW+wrb ; G = sigmoid(Z@gtW+gtb)*Z
    wt_gemm_k<<<dim3(DM/64, BB), 256, 0, stream>>>(sc, tokens, slot, t1);
    gemm512_k<2><<<dim3(BB*SS/64, 8), 256, 0, stream>>>(t1, vW, vB, rr, t2, BB*SS);
    gemm512_k<0><<<dim3(BB*SS/64, 8), 256, 0, stream>>>(t2, wrW, wrB, nullptr, t1, BB*SS);
    gemm512_k<1><<<dim3(BB*SS/64, 8), 256, 0, stream>>>(t1, gtW, gtB, t1, t2, BB*SS);
    mem_ln_k<<<BB*SS, 256, 0, stream>>>(mem, t2, mg, mb);
  }

  // read phase
  gemm512_k<0><<<dim3(BB*SS/64, 8), 256, 0, stream>>>(mem, rkW, rkB, nullptr, kkb, BB*SS);
  prep_k<<<dim3(DM/64, BB), 256, 0, stream>>>(rqW, kkb, P);
  cb_k<<<BB, 64, 0, stream>>>(rqB, kkb, cbuf);
  scores_k<<<dim3(TT/64, BB), 256, 0, stream>>>(tokens, P, cbuf, sc);
  binding_k<<<BT/4, 256, 0, stream>>>(sc, amask);
  colsum_k<<<BB, 256, 0, stream>>>(sc, rws, nullptr, 1);
  gemm512_k<0><<<dim3(BB*SS/64, 8), 256, 0, stream>>>(mem, rvW, rvB, nullptr, t1, BB*SS);
  toksum_k<<<BB, 256, 0, stream>>>(tokens, amask, tsum);
  final_k<<<BB, 256, 0, stream>>>(tsum, rws, t1, amask, fW, fB, cW, cB, (float*)d_out);
}

// Round 4
// 1115.608 us; speedup vs baseline: 2.4463x; 2.4463x over previous
//
#include <hip/hip_runtime.h>
#include <hip/hip_bf16.h>
#include <math.h>

#define BB 32
#define TT 2048
#define DM 512
#define SS 64
#define BT (BB*TT)
#define NSTEPS 4
#define SCALE 0.044194173824159216f

typedef unsigned short u16;
typedef __attribute__((ext_vector_type(8))) short s16x8;
typedef __attribute__((ext_vector_type(4))) float f32x4;

__device__ __forceinline__ u16 f2b(float x){
  __hip_bfloat16 h = __float2bfloat16(x);
  return *reinterpret_cast<u16*>(&h);
}
__device__ __forceinline__ float b2f(u16 u){
  __hip_bfloat16 h;
  *reinterpret_cast<u16*>(&h) = u;
  return __bfloat162float(h);
}

static __device__ __forceinline__ float wave_reduce_sum(float v){
  #pragma unroll
  for (int off=32; off; off>>=1) v += __shfl_down(v, off);
  return v;
}

// ---------------- embedding + token LN (bf16 out) ----------------
__global__ __launch_bounds__(256) void embed_ln_k(const int* __restrict__ ids,
    const float* __restrict__ temb, const float* __restrict__ pemb,
    const float* __restrict__ g, const float* __restrict__ be, u16* __restrict__ out){
  int row = blockIdx.x;
  int t = row & (TT-1);
  int id = ids[row];
  int d = threadIdx.x;
  const float* te = temb + (size_t)id*DM;
  const float* pe = pemb + (size_t)t*DM;
  float x0 = te[d] + pe[d];
  float x1 = te[d+256] + pe[d+256];
  float s1 = x0+x1, s2 = x0*x0 + x1*x1;
  s1 = wave_reduce_sum(s1); s2 = wave_reduce_sum(s2);
  __shared__ float r1[4], r2[4];
  int lane = d & 63, w = d>>6;
  if (lane==0){ r1[w]=s1; r2[w]=s2; }
  __syncthreads();
  float S1 = r1[0]+r1[1]+r1[2]+r1[3];
  float S2 = r2[0]+r2[1]+r2[2]+r2[3];
  float mu = S1 * (1.f/DM);
  float var = S2*(1.f/DM) - mu*mu;
  float rs = rsqrtf(var + 1e-5f);
  u16* orow = out + (size_t)row*DM;
  orow[d]     = f2b((x0-mu)*rs*g[d] + be[d]);
  orow[d+256] = f2b((x1-mu)*rs*g[d+256] + be[d+256]);
}

// ---------------- generic NT bf16 MFMA gemm: C[M][512] = A[M][512] @ Bm[512][512]^T ----------------
// EPI: 0 = bf16(acc+bias[n]) ; 1 = bf16(acc + rowv[m]*bias[n]) ;
//      2 = f32( b2f(mul[m,n]) * sigmoid(acc+bias[n]) ) ; 3 = f32(acc+bias[n]) ; 4 = bf16(acc*scalep)
template<int EPI>
__global__ __launch_bounds__(128) void ntgemm_k(const u16* __restrict__ A,
    const u16* __restrict__ Bm, const float* __restrict__ bias,
    const u16* __restrict__ mulb, const float* __restrict__ rowv,
    void* __restrict__ Cout, float scalep){
  int m0 = blockIdx.x*32 + (threadIdx.x>>6)*16;
  int n0 = blockIdx.y*64;
  int l = threadIdx.x & 63;
  int lr = l & 15, lk = (l>>4)*8;
  const u16* Arow = A + (size_t)(m0 + lr)*512 + lk;
  const u16* B0   = Bm + (size_t)(n0 + lr)*512 + lk;
  f32x4 acc[4] = {};
  #pragma unroll
  for (int k0=0;k0<512;k0+=32){
    s16x8 a = *(const s16x8*)(Arow + k0);
    #pragma unroll
    for (int j=0;j<4;j++){
      s16x8 b = *(const s16x8*)(B0 + (size_t)j*16*512 + k0);
      acc[j] = __builtin_amdgcn_mfma_f32_16x16x32_bf16(a, b, acc[j], 0,0,0);
    }
  }
  int mbase = m0 + (l>>4)*4;
  #pragma unroll
  for (int j=0;j<4;j++){
    int n = n0 + j*16 + lr;
    #pragma unroll
    for (int r=0;r<4;r++){
      int m = mbase + r;
      float v = acc[j][r];
      if (EPI==0){ ((u16*)Cout)[(size_t)m*512 + n] = f2b(v + bias[n]); }
      if (EPI==1){ ((u16*)Cout)[(size_t)m*512 + n] = f2b(v + rowv[m]*bias[n]); }
      if (EPI==2){
        float z = v + bias[n];
        float sg = 1.f/(1.f + expf(-z));
        ((float*)Cout)[(size_t)m*512 + n] = b2f(mulb[(size_t)m*512 + n]) * sg;
      }
      if (EPI==3){ ((float*)Cout)[(size_t)m*512 + n] = v + bias[n]; }
      if (EPI==4){ ((u16*)Cout)[(size_t)m*512 + n] = f2b(v * scalep); }
    }
  }
}

// ---------------- fused scores + top8 softmax binding + colsum partial ----------------
// scores[t,s] = sum_d tok[b,t,d]*Pt[b,s,d] + cb[b,s]; then clip/top8/softmax/mask.
// writes BNDT[b][s][t] bf16 and cspart[b][ttile][s].
__global__ __launch_bounds__(256) void bind_k(const u16* __restrict__ tok,
    const u16* __restrict__ Pt, const float* __restrict__ cbuf, const int* __restrict__ mask,
    u16* __restrict__ BNDT, float* __restrict__ cspart){
  int b = blockIdx.y, t0 = blockIdx.x*64;
  int tid = threadIdx.x, w = tid>>6, l = tid&63;
  int lr = l&15, lk = (l>>4)*8;
  __shared__ float sc[64][65];
  __shared__ u16 bt[64][72];
  __shared__ float csred[4][64];
  const u16* Arow = tok + ((size_t)(b*TT + t0 + 16*w + lr))*512 + lk;
  const u16* Brow = Pt + ((size_t)(b*SS + lr))*512 + lk;
  f32x4 acc[4] = {};
  #pragma unroll
  for (int k0=0;k0<512;k0+=32){
    s16x8 a = *(const s16x8*)(Arow + k0);
    #pragma unroll
    for (int j=0;j<4;j++){
      s16x8 bb = *(const s16x8*)(Brow + (size_t)j*16*512 + k0);
      acc[j] = __builtin_amdgcn_mfma_f32_16x16x32_bf16(a, bb, acc[j], 0,0,0);
    }
  }
  #pragma unroll
  for (int j=0;j<4;j++)
    #pragma unroll
    for (int r=0;r<4;r++)
      sc[16*w + (l>>4)*4 + r][16*j + lr] = acc[j][r];
  __syncthreads();
  float cbv = cbuf[b*SS + l];
  float csum = 0.f;
  for (int r=0;r<16;r++){
    int row = 16*w + r;
    float sv = sc[row][l] + cbv;
    sv = fminf(fmaxf(sv, -10.f), 10.f);
    float work = sv;
    float topmax = 0.f;
    bool sel = false;
    #pragma unroll
    for (int it=0; it<8; ++it){
      float v = work; int idx = l;
      #pragma unroll
      for (int off=32; off; off>>=1){
        float ov = __shfl_xor(v, off);
        int oi = __shfl_xor(idx, off);
        if (ov > v || (ov == v && oi < idx)){ v = ov; idx = oi; }
      }
      if (it==0) topmax = v;
      if (l == idx){ sel = true; work = -INFINITY; }
    }
    float e = sel ? expf(sv - topmax) : 0.f;
    float tot = e;
    #pragma unroll
    for (int off=32; off; off>>=1) tot += __shfl_xor(tot, off);
    int mv = mask[b*TT + t0 + row];
    float wv = mv ? (e / tot) : 0.f;
    bt[l][row] = f2b(wv);
    csum += wv;
  }
  csred[w][l] = csum;
  __syncthreads();
  if (w==0){
    float s = csred[0][l]+csred[1][l]+csred[2][l]+csred[3][l];
    cspart[((size_t)b*32 + blockIdx.x)*64 + l] = s;
  }
  int s = tid>>2, ch = (tid&3)*16;
  u16* dst = BNDT + ((size_t)(b*SS + s))*TT + t0 + ch;
  s16x8 w0 = *(const s16x8*)&bt[s][ch];
  s16x8 w1 = *(const s16x8*)&bt[s][ch+8];
  *(s16x8*)dst = w0;
  *(s16x8*)(dst+8) = w1;
}

// ---------------- colsum reduce: slot (clamped), rr, raw ----------------
__global__ __launch_bounds__(64) void csred_k(const float* __restrict__ cspart,
    float* __restrict__ slot, float* __restrict__ rr, float* __restrict__ raw){
  int b = blockIdx.x, s = threadIdx.x;
  float t = 0.f;
  for (int k=0;k<32;k++) t += cspart[((size_t)b*32 + k)*64 + s];
  raw[b*SS+s] = t;
  float sl = fmaxf(t, 1e-6f);
  slot[b*SS+s] = sl;
  rr[b*SS+s] = t/sl;
}

// ---------------- wt: part[ks][b*64+s][d] = sum_{t in slice} BNDT[b,s,t]*tok[b,t,d] ----------------
__global__ __launch_bounds__(256) void wt_k(const u16* __restrict__ BNDT,
    const u16* __restrict__ tok, float* __restrict__ part){
  int dgrp = blockIdx.x, b = blockIdx.y, ks = blockIdx.z;
  int tid = threadIdx.x, w = tid>>6, l = tid&63;
  int lr = l&15, lk = (l>>4)*8;
  __shared__ u16 tk[128][72];
  f32x4 acc[8] = {};
  int trow = tid>>2, dseg = (tid&3)*32;
  const u16* tokbase = tok + ((size_t)b*TT)*512 + dgrp*128;
  const u16* Abase = BNDT + ((size_t)(b*SS + 16*w + lr))*TT;
  for (int chunk=0; chunk<8; ++chunk){
    int tb = ks*512 + chunk*64;
    const u16* src = tokbase + (size_t)(tb + trow)*512 + dseg;
    s16x8 v0 = *(const s16x8*)(src);
    s16x8 v1 = *(const s16x8*)(src+8);
    s16x8 v2 = *(const s16x8*)(src+16);
    s16x8 v3 = *(const s16x8*)(src+24);
    #pragma unroll
    for (int e=0;e<8;e++){
      tk[dseg+e][trow]    = (u16)v0[e];
      tk[dseg+8+e][trow]  = (u16)v1[e];
      tk[dseg+16+e][trow] = (u16)v2[e];
      tk[dseg+24+e][trow] = (u16)v3[e];
    }
    __syncthreads();
    #pragma unroll
    for (int kst=0;kst<2;kst++){
      s16x8 a = *(const s16x8*)(Abase + tb + kst*32 + lk);
      #pragma unroll
      for (int nt=0;nt<8;nt++){
        s16x8 bb = *(const s16x8*)&tk[nt*16 + lr][kst*32 + lk];
        acc[nt] = __builtin_amdgcn_mfma_f32_16x16x32_bf16(a, bb, acc[nt], 0,0,0);
      }
    }
    __syncthreads();
  }
  float* dst = part + (size_t)ks*2048*512 + ((size_t)(b*SS))*512 + dgrp*128;
  #pragma unroll
  for (int nt=0;nt<8;nt++){
    int d = nt*16 + lr;
    #pragma unroll
    for (int r=0;r<4;r++){
      int s = 16*w + (l>>4)*4 + r;
      dst[(size_t)s*512 + d] = acc[nt][r];
    }
  }
}

// ---------------- wt reduce + /slot -> bf16 ----------------
__global__ __launch_bounds__(256) void wtred_k(const float* __restrict__ part,
    const float* __restrict__ slot, u16* __restrict__ t1h){
  int i = blockIdx.x*256 + threadIdx.x;
  int row = i>>9;
  float v = part[i] + part[i + 2048*512] + part[i + 2*2048*512] + part[i + 3*2048*512];
  t1h[i] = f2b(v / slot[row]);
}

// ---------------- cb[row] = dot(mem[row,:], wcb) + cb0 ----------------
__global__ __launch_bounds__(256) void cb_k(const float* __restrict__ mem,
    const float* __restrict__ wcb, const float* __restrict__ cb0p, float* __restrict__ cb){
  int row = blockIdx.x*4 + (threadIdx.x>>6), l = threadIdx.x&63;
  const float* r = mem + (size_t)row*512;
  float s = 0.f;
  #pragma unroll
  for (int k=0;k<8;k++) s += r[l + 64*k]*wcb[l + 64*k];
  #pragma unroll
  for (int off=32; off; off>>=1) s += __shfl_xor(s, off);
  if (l==0) cb[row] = s + cb0p[0];
}

// ---------------- matvec: out[i] = scale * dot(W[i,:], v) ----------------
__global__ __launch_bounds__(256) void matvec_k(const float* __restrict__ W,
    const float* __restrict__ v, float* __restrict__ out){
  int i = blockIdx.x*4 + (threadIdx.x>>6), l = threadIdx.x&63;
  const float* r = W + (size_t)i*512;
  float s = 0.f;
  #pragma unroll
  for (int k=0;k<8;k++) s += r[l + 64*k]*v[l + 64*k];
  #pragma unroll
  for (int off=32; off; off>>=1) s += __shfl_xor(s, off);
  if (l==0) out[i] = s * SCALE;
}

// ---------------- two scaled dots (cb0, cb0_r) ----------------
__global__ __launch_bounds__(128) void dot2_k(const float* __restrict__ a0, const float* __restrict__ b0,
    const float* __restrict__ a1, const float* __restrict__ b1, float* __restrict__ out){
  int w = threadIdx.x>>6, l = threadIdx.x&63;
  const float* a = w ? a1 : a0;
  const float* b = w ? b1 : b0;
  float s = 0.f;
  #pragma unroll
  for (int k=0;k<8;k++) s += a[l + 64*k]*b[l + 64*k];
  #pragma unroll
  for (int off=32; off; off>>=1) s += __shfl_xor(s, off);
  if (l==0) out[w] = s * SCALE;
}

// ---------------- transpose + convert fp32 [512][512] -> bf16 [512][512]^T ----------------
__global__ __launch_bounds__(256) void tconv_k(const float* __restrict__ in, u16* __restrict__ out){
  __shared__ float t[32][33];
  int c0 = blockIdx.x*32, r0 = blockIdx.y*32;
  int cx = threadIdx.x&31, ry = threadIdx.x>>5;
  #pragma unroll
  for (int i=0;i<4;i++){ int r = ry + i*8; t[r][cx] = in[(size_t)(r0+r)*512 + c0+cx]; }
  __syncthreads();
  #pragma unroll
  for (int i=0;i<4;i++){ int r = ry + i*8; out[(size_t)(c0+r)*512 + r0+cx] = f2b(t[cx][r]); }
}

// ---------------- straight cast fp32 -> bf16 ----------------
__global__ __launch_bounds__(256) void conv_k(const float* __restrict__ in, u16* __restrict__ out){
  int i = blockIdx.x*256 + threadIdx.x;
  out[i] = f2b(in[i]);
}

// ---------------- memory init (fp32 + bf16 mirror) ----------------
__global__ __launch_bounds__(256) void meminit_k(const float* __restrict__ src,
    float* __restrict__ mem, u16* __restrict__ memh){
  int i = blockIdx.x*256 + threadIdx.x;
  float v = src[i & (SS*DM-1)];
  mem[i] = v;
  memh[i] = f2b(v);
}

// ---------------- mem = LN(0.9*mem + 0.1*w3) -> fp32 + bf16 mirror ----------------
__global__ __launch_bounds__(256) void mem_ln_k(float* __restrict__ mem, const float* __restrict__ w3,
    const float* __restrict__ g, const float* __restrict__ be, u16* __restrict__ memh){
  int row = blockIdx.x;
  int d = threadIdx.x;
  float* mrow = mem + (size_t)row*DM;
  const float* wrow = w3 + (size_t)row*DM;
  float x0 = 0.9f*mrow[d]     + 0.1f*wrow[d];
  float x1 = 0.9f*mrow[d+256] + 0.1f*wrow[d+256];
  float s1 = x0+x1, s2 = x0*x0 + x1*x1;
  s1 = wave_reduce_sum(s1); s2 = wave_reduce_sum(s2);
  __shared__ float r1[4], r2[4];
  int lane = d & 63, w = d>>6;
  if (lane==0){ r1[w]=s1; r2[w]=s2; }
  __syncthreads();
  float S1 = r1[0]+r1[1]+r1[2]+r1[3];
  float S2 = r2[0]+r2[1]+r2[2]+r2[3];
  float mu = S1 * (1.f/DM);
  float var = S2*(1.f/DM) - mu*mu;
  float rs = rsqrtf(var + 1e-5f);
  float y0 = (x0-mu)*rs*g[d] + be[d];
  float y1 = (x1-mu)*rs*g[d+256] + be[d+256];
  mrow[d] = y0; mrow[d+256] = y1;
  memh[(size_t)row*DM + d] = f2b(y0);
  memh[(size_t)row*DM + d+256] = f2b(y1);
}

// ---------------- masked token sum partials ----------------
__global__ __launch_bounds__(256) void tokpart_k(const u16* __restrict__ tok,
    const int* __restrict__ mask, float* __restrict__ tp){
  int b = blockIdx.x, sl = blockIdx.y, d = threadIdx.x;
  float s0=0.f, s1=0.f;
  for (int t = sl*128; t < sl*128+128; ++t){
    float m = (float)mask[b*TT + t];
    const u16* row = tok + ((size_t)(b*TT + t))*512;
    s0 += m*b2f(row[d]);
    s1 += m*b2f(row[d+256]);
  }
  tp[((size_t)(b*16 + sl))*512 + d] = s0;
  tp[((size_t)(b*16 + sl))*512 + d+256] = s1;
}

// ---------------- final: ctx = rws@rv ; fuse ; pool ; classify ----------------
__global__ __launch_bounds__(256) void final_k(const float* __restrict__ tp,
    const float* __restrict__ rws, const float* __restrict__ rv,
    const int* __restrict__ mask, const float* __restrict__ fuseW, const float* __restrict__ fuseb,
    const float* __restrict__ clsW, const float* __restrict__ clsb, float* __restrict__ out){
  int b = blockIdx.x, tid = threadIdx.x;
  __shared__ float cat[2*DM];
  __shared__ float pooled[DM];
  __shared__ float dred[4];
  float dn = 0.f;
  for (int t=tid; t<TT; t+=256) dn += (float)mask[b*TT+t];
  dn = wave_reduce_sum(dn);
  if ((tid&63)==0) dred[tid>>6]=dn;
  __syncthreads();
  float denom = dred[0]+dred[1]+dred[2]+dred[3];
  for (int d=tid; d<DM; d+=256){
    float ts = 0.f;
    for (int sl=0; sl<16; sl++) ts += tp[((size_t)(b*16+sl))*512 + d];
    cat[d] = ts;
    float c = 0.f;
    for (int s=0;s<SS;s++) c += rws[b*SS+s]*rv[((size_t)b*SS+s)*DM + d];
    cat[DM+d] = c;
  }
  __syncthreads();
  float dinv = 1.f/fmaxf(denom, 1.f);
  for (int d=tid; d<DM; d+=256){
    float acc = 0.f;
    for (int k=0;k<2*DM;k++) acc += cat[k]*fuseW[(size_t)k*DM + d];
    pooled[d] = (acc + denom*fuseb[d])*dinv;
  }
  __syncthreads();
  if (tid < 8){
    float acc=0.f;
    for (int d=0;d<DM;d++) acc += pooled[d]*clsW[d*8+tid];
    out[b*8+tid] = acc + clsb[tid];
  }
}

extern "C" void kernel_launch(void* const* d_in, const int* in_sizes, int n_in,
                              void* d_out, int out_size, void* d_ws, size_t ws_size,
                              hipStream_t stream){
  (void)in_sizes; (void)n_in; (void)out_size; (void)ws_size;
  const int*   ids   = (const int*)d_in[0];
  const int*   amask = (const int*)d_in[1];
  const float* temb  = (const float*)d_in[2];
  const float* pemb  = (const float*)d_in[3];
  const float* mem0  = (const float*)d_in[4];
  const float* qW=(const float*)d_in[5],  *qB=(const float*)d_in[6];
  const float* kW=(const float*)d_in[7],  *kB=(const float*)d_in[8];
  const float* vW=(const float*)d_in[9],  *vB=(const float*)d_in[10];
  const float* wrW=(const float*)d_in[11],*wrB=(const float*)d_in[12];
  const float* gtW=(const float*)d_in[13],*gtB=(const float*)d_in[14];
  const float* rqW=(const float*)d_in[15],*rqB=(const float*)d_in[16];
  const float* rkW=(const float*)d_in[17],*rkB=(const float*)d_in[18];
  const float* rvW=(const float*)d_in[19],*rvB=(const float*)d_in[20];
  const float* fW=(const float*)d_in[21], *fB=(const float*)d_in[22];
  const float* cW=(const float*)d_in[23], *cB=(const float*)d_in[24];
  const float* tg=(const float*)d_in[25], *tb=(const float*)d_in[26];
  const float* mg=(const float*)d_in[27], *mb=(const float*)d_in[28];

  // ---- workspace layout (~110 MB) ----
  char* p = (char*)d_ws;
  size_t off = 0;
  auto alloc = [&](size_t bytes)->char*{ char* r = p + off; off += (bytes + 255) & ~(size_t)255; return r; };
  u16*   tokens = (u16*)  alloc((size_t)BT*DM*2);        // 67.1 MB
  u16*   Pt     = (u16*)  alloc((size_t)BB*SS*DM*2);     // 2.1 MB
  u16*   BNDT   = (u16*)  alloc((size_t)BB*SS*TT*2);     // 8.4 MB
  float* cspart = (float*)alloc((size_t)BB*32*64*4);     // 0.26 MB
  float* wtpart = (float*)alloc((size_t)4*2048*512*4);   // 16.8 MB (hosts aliases below)
  u16*   t1h    = (u16*)  alloc((size_t)2048*512*2);
  u16*   t2h    = (u16*)  alloc((size_t)2048*512*2);
  u16*   zh     = (u16*)  alloc((size_t)2048*512*2);
  float* mem    = (float*)alloc((size_t)BB*SS*DM*4);
  u16*   memh   = (u16*)  alloc((size_t)BB*SS*DM*2);
  u16*   vWT    = (u16*)  alloc(512*512*2);
  u16*   wrWT   = (u16*)  alloc(512*512*2);
  u16*   gtWT   = (u16*)  alloc(512*512*2);
  u16*   rvWT   = (u16*)  alloc(512*512*2);
  u16*   WqkT   = (u16*)  alloc(512*512*2);
  u16*   WqkT_r = (u16*)  alloc(512*512*2);
  float* bq     = (float*)alloc(512*4);
  float* bq_r   = (float*)alloc(512*4);
  float* wcb    = (float*)alloc(512*4);
  float* wcb_r  = (float*)alloc(512*4);
  float* cb0s   = (float*)alloc(256);
  float* cbuf   = (float*)alloc(2048*4);
  float* slot   = (float*)alloc(2048*4);
  float* rr     = (float*)alloc(2048*4);
  float* raw    = (float*)alloc(2048*4);
  // aliases inside wtpart (liveness-disjoint):
  float* rv32   = wtpart;                       // read phase only
  float* tspart = wtpart + 1048576;             // read phase only
  float* gh32   = wtpart + 2097152;             // after wtred, before next wt
  u16*   qWb    = (u16*)((char*)wtpart + 12582912);  // precompute only
  u16*   kWb    = qWb + 512*512;
  u16*   rqWb   = kWb + 512*512;
  u16*   rkWb   = rqWb + 512*512;

  // ---- precompute ----
  conv_k<<<1024, 256, 0, stream>>>(qW, qWb);
  conv_k<<<1024, 256, 0, stream>>>(kW, kWb);
  conv_k<<<1024, 256, 0, stream>>>(rqW, rqWb);
  conv_k<<<1024, 256, 0, stream>>>(rkW, rkWb);
  tconv_k<<<dim3(16,16), 256, 0, stream>>>(vW, vWT);
  tconv_k<<<dim3(16,16), 256, 0, stream>>>(wrW, wrWT);
  tconv_k<<<dim3(16,16), 256, 0, stream>>>(gtW, gtWT);
  tconv_k<<<dim3(16,16), 256, 0, stream>>>(rvW, rvWT);
  ntgemm_k<4><<<dim3(16,8), 128, 0, stream>>>(qWb, kWb, nullptr, nullptr, nullptr, WqkT, SCALE);
  ntgemm_k<4><<<dim3(16,8), 128, 0, stream>>>(rqWb, rkWb, nullptr, nullptr, nullptr, WqkT_r, SCALE);
  matvec_k<<<128, 256, 0, stream>>>(qW, kB, bq);
  matvec_k<<<128, 256, 0, stream>>>(rqW, rkB, bq_r);
  matvec_k<<<128, 256, 0, stream>>>(kW, qB, wcb);
  matvec_k<<<128, 256, 0, stream>>>(rkW, rqB, wcb_r);
  dot2_k<<<1, 128, 0, stream>>>(kB, qB, rkB, rqB, cb0s);
  embed_ln_k<<<BT, 256, 0, stream>>>(ids, temb, pemb, tg, tb, tokens);
  meminit_k<<<(BB*SS*DM)/256, 256, 0, stream>>>(mem0, mem, memh);

  // ---- recurrent steps ----
  for (int step=0; step<NSTEPS; ++step){
    ntgemm_k<0><<<dim3(64,8), 128, 0, stream>>>(memh, WqkT, bq, nullptr, nullptr, Pt, 0.f);
    cb_k<<<512, 256, 0, stream>>>(mem, wcb, cb0s, cbuf);
    bind_k<<<dim3(32,32), 256, 0, stream>>>(tokens, Pt, cbuf, amask, BNDT, cspart);
    csred_k<<<32, 64, 0, stream>>>(cspart, slot, rr, raw);
    wt_k<<<dim3(4,32,4), 256, 0, stream>>>(BNDT, tokens, wtpart);
    wtred_k<<<4096, 256, 0, stream>>>(wtpart, slot, t1h);
    ntgemm_k<1><<<dim3(64,8), 128, 0, stream>>>(t1h, vWT, vB, nullptr, rr, t2h, 0.f);
    ntgemm_k<0><<<dim3(64,8), 128, 0, stream>>>(t2h, wrWT, wrB, nullptr, nullptr, zh, 0.f);
    ntgemm_k<2><<<dim3(64,8), 128, 0, stream>>>(zh, gtWT, gtB, zh, nullptr, gh32, 0.f);
    mem_ln_k<<<BB*SS, 256, 0, stream>>>(mem, gh32, mg, mb, memh);
  }

  // ---- read phase ----
  ntgemm_k<0><<<dim3(64,8), 128, 0, stream>>>(memh, WqkT_r, bq_r, nullptr, nullptr, Pt, 0.f);
  cb_k<<<512, 256, 0, stream>>>(mem, wcb_r, cb0s+1, cbuf);
  bind_k<<<dim3(32,32), 256, 0, stream>>>(tokens, Pt, cbuf, amask, BNDT, cspart);
  csred_k<<<32, 64, 0, stream>>>(cspart, slot, rr, raw);
  ntgemm_k<3><<<dim3(64,8), 128, 0, stream>>>(memh, rvWT, rvB, nullptr, nullptr, rv32, 0.f);
  tokpart_k<<<dim3(32,16), 256, 0, stream>>>(tokens, amask, tspart);
  final_k<<<32, 256, 0, stream>>>(tspart, raw, rv32, amask, fW, fB, cW, cB, (float*)d_out);
}

// Round 5
// 914.825 us; speedup vs baseline: 2.9832x; 1.2195x over previous
//
#include <hip/hip_runtime.h>
#include <hip/hip_bf16.h>
#include <math.h>

#define BB 32
#define TT 2048
#define DM 512
#define SS 64
#define BT (BB*TT)
#define NSTEPS 4
#define SCALE 0.044194173824159216f

typedef unsigned short u16;
typedef __attribute__((ext_vector_type(8))) short s16x8;
typedef __attribute__((ext_vector_type(4))) float f32x4;

__device__ __forceinline__ u16 f2b(float x){
  __hip_bfloat16 h = __float2bfloat16(x);
  return *reinterpret_cast<u16*>(&h);
}
__device__ __forceinline__ float b2f(u16 u){
  __hip_bfloat16 h;
  *reinterpret_cast<u16*>(&h) = u;
  return __bfloat162float(h);
}

static __device__ __forceinline__ float wave_reduce_sum(float v){
  #pragma unroll
  for (int off=32; off; off>>=1) v += __shfl_down(v, off);
  return v;
}

// ---------------- embedding + token LN (bf16 out) ----------------
__global__ __launch_bounds__(256) void embed_ln_k(const int* __restrict__ ids,
    const float* __restrict__ temb, const float* __restrict__ pemb,
    const float* __restrict__ g, const float* __restrict__ be, u16* __restrict__ out){
  int row = blockIdx.x;
  int t = row & (TT-1);
  int id = ids[row];
  int d = threadIdx.x;
  const float* te = temb + (size_t)id*DM;
  const float* pe = pemb + (size_t)t*DM;
  float x0 = te[d] + pe[d];
  float x1 = te[d+256] + pe[d+256];
  float s1 = x0+x1, s2 = x0*x0 + x1*x1;
  s1 = wave_reduce_sum(s1); s2 = wave_reduce_sum(s2);
  __shared__ float r1[4], r2[4];
  int lane = d & 63, w = d>>6;
  if (lane==0){ r1[w]=s1; r2[w]=s2; }
  __syncthreads();
  float S1 = r1[0]+r1[1]+r1[2]+r1[3];
  float S2 = r2[0]+r2[1]+r2[2]+r2[3];
  float mu = S1 * (1.f/DM);
  float var = S2*(1.f/DM) - mu*mu;
  float rs = rsqrtf(var + 1e-5f);
  u16* orow = out + (size_t)row*DM;
  orow[d]     = f2b((x0-mu)*rs*g[d] + be[d]);
  orow[d+256] = f2b((x1-mu)*rs*g[d+256] + be[d+256]);
}

// ---------------- generic NT bf16 MFMA gemm: C[M][512] = A[M][512] @ Bm[512][512]^T ----------------
// EPI: 0 = bf16(acc+bias[n]) ; 1 = bf16(acc + rowv[m]*bias[n]) ;
//      2 = f32( b2f(mul[m,n]) * sigmoid(acc+bias[n]) ) ; 3 = f32(acc+bias[n]) ; 4 = bf16(acc*scalep)
template<int EPI>
__global__ __launch_bounds__(128) void ntgemm_k(const u16* __restrict__ A,
    const u16* __restrict__ Bm, const float* __restrict__ bias,
    const u16* __restrict__ mulb, const float* __restrict__ rowv,
    void* __restrict__ Cout, float scalep){
  int m0 = blockIdx.x*32 + (threadIdx.x>>6)*16;
  int n0 = blockIdx.y*64;
  int l = threadIdx.x & 63;
  int lr = l & 15, lk = (l>>4)*8;
  const u16* Arow = A + (size_t)(m0 + lr)*512 + lk;
  const u16* B0   = Bm + (size_t)(n0 + lr)*512 + lk;
  f32x4 acc[4] = {};
  #pragma unroll
  for (int k0=0;k0<512;k0+=32){
    s16x8 a = *(const s16x8*)(Arow + k0);
    #pragma unroll
    for (int j=0;j<4;j++){
      s16x8 b = *(const s16x8*)(B0 + (size_t)j*16*512 + k0);
      acc[j] = __builtin_amdgcn_mfma_f32_16x16x32_bf16(a, b, acc[j], 0,0,0);
    }
  }
  int mbase = m0 + (l>>4)*4;
  #pragma unroll
  for (int j=0;j<4;j++){
    int n = n0 + j*16 + lr;
    #pragma unroll
    for (int r=0;r<4;r++){
      int m = mbase + r;
      float v = acc[j][r];
      if (EPI==0){ ((u16*)Cout)[(size_t)m*512 + n] = f2b(v + bias[n]); }
      if (EPI==1){ ((u16*)Cout)[(size_t)m*512 + n] = f2b(v + rowv[m]*bias[n]); }
      if (EPI==2){
        float z = v + bias[n];
        float sg = 1.f/(1.f + expf(-z));
        ((float*)Cout)[(size_t)m*512 + n] = b2f(mulb[(size_t)m*512 + n]) * sg;
      }
      if (EPI==3){ ((float*)Cout)[(size_t)m*512 + n] = v + bias[n]; }
      if (EPI==4){ ((u16*)Cout)[(size_t)m*512 + n] = f2b(v * scalep); }
    }
  }
}

// ---------------- fused scores + top8 softmax binding + colsum partial ----------------
// scores[t,s] = sum_d tok[b,t,d]*Pt[b,s,d] + cb[b,s]; then clip/top8/softmax/mask.
// Top-8 runs per 16-lane group (4 rows in parallel per wave) directly on the MFMA
// C-fragments: group g = l>>4 holds row (16w+4g+r), lane lr holds cols {16j+lr}.
// Writes BNDT[b][s][t] bf16 and cspart[b][ttile][s].
__global__ __launch_bounds__(256) void bind_k(const u16* __restrict__ tok,
    const u16* __restrict__ Pt, const float* __restrict__ cbuf, const int* __restrict__ mask,
    u16* __restrict__ BNDT, float* __restrict__ cspart){
  int b = blockIdx.y, t0 = blockIdx.x*64;
  int tid = threadIdx.x, w = tid>>6, l = tid&63;
  int lr = l&15, g = l>>4, lk = g*8;
  __shared__ u16 bt[64][72];
  __shared__ float cs[16][64];
  const u16* Arow = tok + ((size_t)(b*TT + t0 + 16*w + lr))*512 + lk;
  const u16* Brow = Pt + ((size_t)(b*SS + lr))*512 + lk;
  f32x4 acc[4] = {};
  #pragma unroll
  for (int k0=0;k0<512;k0+=32){
    s16x8 a = *(const s16x8*)(Arow + k0);
    #pragma unroll
    for (int j=0;j<4;j++){
      s16x8 bb = *(const s16x8*)(Brow + (size_t)j*16*512 + k0);
      acc[j] = __builtin_amdgcn_mfma_f32_16x16x32_bf16(a, bb, acc[j], 0,0,0);
    }
  }
  float cbv[4];
  #pragma unroll
  for (int j=0;j<4;j++) cbv[j] = cbuf[b*SS + 16*j + lr];
  float cssum[4] = {0.f,0.f,0.f,0.f};
  #pragma unroll
  for (int r=0;r<4;r++){
    int row = 16*w + 4*g + r;
    float sv[4], work[4];
    #pragma unroll
    for (int j=0;j<4;j++){
      float x = acc[j][r] + cbv[j];
      x = fminf(fmaxf(x, -10.f), 10.f);
      sv[j] = x; work[j] = x;
    }
    bool sel[4] = {false,false,false,false};
    float topmax = 0.f;
    #pragma unroll
    for (int it=0; it<8; ++it){
      float lv = work[0]; int lc = lr;
      #pragma unroll
      for (int j=1;j<4;j++){ if (work[j] > lv){ lv = work[j]; lc = 16*j + lr; } }
      #pragma unroll
      for (int off=1; off<16; off<<=1){
        float ov = __shfl_xor(lv, off);
        int oc = __shfl_xor(lc, off);
        if (ov > lv || (ov == lv && oc < lc)){ lv = ov; lc = oc; }
      }
      if (it==0) topmax = lv;
      if ((lc & 15) == lr){ int jj = lc >> 4; sel[jj] = true; work[jj] = -INFINITY; }
    }
    float e[4], tot = 0.f;
    #pragma unroll
    for (int j=0;j<4;j++){ e[j] = sel[j] ? expf(sv[j]-topmax) : 0.f; tot += e[j]; }
    #pragma unroll
    for (int off=1; off<16; off<<=1) tot += __shfl_xor(tot, off);
    int mv = mask[b*TT + t0 + row];
    float inv = mv ? 1.f/tot : 0.f;
    #pragma unroll
    for (int j=0;j<4;j++){
      float wv = e[j]*inv;
      bt[16*j + lr][row] = f2b(wv);
      cssum[j] += wv;
    }
  }
  #pragma unroll
  for (int j=0;j<4;j++) cs[w*4+g][16*j+lr] = cssum[j];
  __syncthreads();
  if (tid < 64){
    float s = 0.f;
    #pragma unroll
    for (int k=0;k<16;k++) s += cs[k][tid];
    cspart[((size_t)b*32 + blockIdx.x)*64 + tid] = s;
  }
  int s = tid>>2, ch = (tid&3)*16;
  u16* dst = BNDT + ((size_t)(b*SS + s))*TT + t0 + ch;
  s16x8 w0 = *(const s16x8*)&bt[s][ch];
  s16x8 w1 = *(const s16x8*)&bt[s][ch+8];
  *(s16x8*)dst = w0;
  *(s16x8*)(dst+8) = w1;
}

// ---------------- colsum reduce: slot (clamped), rr, raw ----------------
__global__ __launch_bounds__(64) void csred_k(const float* __restrict__ cspart,
    float* __restrict__ slot, float* __restrict__ rr, float* __restrict__ raw){
  int b = blockIdx.x, s = threadIdx.x;
  float t = 0.f;
  for (int k=0;k<32;k++) t += cspart[((size_t)b*32 + k)*64 + s];
  raw[b*SS+s] = t;
  float sl = fmaxf(t, 1e-6f);
  slot[b*SS+s] = sl;
  rr[b*SS+s] = t/sl;
}

// ---------------- wt: part[ks][b*64+s][d] = sum_{t in slice} BNDT[b,s,t]*tok[b,t,d] ----------------
// LDS transpose stores swizzled: element t of column d stored at col (t + 8*((d>>5)&3)) & 63
// to spread the four 32-d segments across banks (4-way -> ~2-way).
__global__ __launch_bounds__(256) void wt_k(const u16* __restrict__ BNDT,
    const u16* __restrict__ tok, float* __restrict__ part){
  int dgrp = blockIdx.x, b = blockIdx.y, ks = blockIdx.z;
  int tid = threadIdx.x, w = tid>>6, l = tid&63;
  int lr = l&15, lk = (l>>4)*8;
  __shared__ u16 tk[128][72];
  f32x4 acc[8] = {};
  int trow = tid>>2, dseg = (tid&3)*32;
  const u16* tokbase = tok + ((size_t)b*TT)*512 + dgrp*128;
  const u16* Abase = BNDT + ((size_t)(b*SS + 16*w + lr))*TT;
  for (int chunk=0; chunk<8; ++chunk){
    int tb = ks*512 + chunk*64;
    const u16* src = tokbase + (size_t)(tb + trow)*512 + dseg;
    s16x8 v0 = *(const s16x8*)(src);
    s16x8 v1 = *(const s16x8*)(src+8);
    s16x8 v2 = *(const s16x8*)(src+16);
    s16x8 v3 = *(const s16x8*)(src+24);
    #pragma unroll
    for (int e=0;e<8;e++){
      int d0 = dseg+e, d1 = dseg+8+e, d2 = dseg+16+e, d3 = dseg+24+e;
      tk[d0][(trow + 8*((d0>>5)&3)) & 63] = (u16)v0[e];
      tk[d1][(trow + 8*((d1>>5)&3)) & 63] = (u16)v1[e];
      tk[d2][(trow + 8*((d2>>5)&3)) & 63] = (u16)v2[e];
      tk[d3][(trow + 8*((d3>>5)&3)) & 63] = (u16)v3[e];
    }
    __syncthreads();
    #pragma unroll
    for (int kst=0;kst<2;kst++){
      s16x8 a = *(const s16x8*)(Abase + tb + kst*32 + lk);
      #pragma unroll
      for (int nt=0;nt<8;nt++){
        int dd = nt*16 + lr;
        int cb2 = (kst*32 + lk + 8*((dd>>5)&3)) & 63;
        s16x8 bb = *(const s16x8*)&tk[dd][cb2];
        acc[nt] = __builtin_amdgcn_mfma_f32_16x16x32_bf16(a, bb, acc[nt], 0,0,0);
      }
    }
    __syncthreads();
  }
  float* dst = part + (size_t)ks*2048*512 + ((size_t)(b*SS))*512 + dgrp*128;
  #pragma unroll
  for (int nt=0;nt<8;nt++){
    int d = nt*16 + lr;
    #pragma unroll
    for (int r=0;r<4;r++){
      int s = 16*w + (l>>4)*4 + r;
      dst[(size_t)s*512 + d] = acc[nt][r];
    }
  }
}

// ---------------- wt reduce + /slot -> bf16 ----------------
__global__ __launch_bounds__(256) void wtred_k(const float* __restrict__ part,
    const float* __restrict__ slot, u16* __restrict__ t1h){
  int i = blockIdx.x*256 + threadIdx.x;
  int row = i>>9;
  float v = part[i] + part[i + 2048*512] + part[i + 2*2048*512] + part[i + 3*2048*512];
  t1h[i] = f2b(v / slot[row]);
}

// ---------------- cb[row] = dot(mem[row,:], wcb) + cb0 ----------------
__global__ __launch_bounds__(256) void cb_k(const float* __restrict__ mem,
    const float* __restrict__ wcb, const float* __restrict__ cb0p, float* __restrict__ cb){
  int row = blockIdx.x*4 + (threadIdx.x>>6), l = threadIdx.x&63;
  const float* r = mem + (size_t)row*512;
  float s = 0.f;
  #pragma unroll
  for (int k=0;k<8;k++) s += r[l + 64*k]*wcb[l + 64*k];
  #pragma unroll
  for (int off=32; off; off>>=1) s += __shfl_xor(s, off);
  if (l==0) cb[row] = s + cb0p[0];
}

// ---------------- matvec: out[i] = scale * dot(W[i,:], v) ----------------
__global__ __launch_bounds__(256) void matvec_k(const float* __restrict__ W,
    const float* __restrict__ v, float* __restrict__ out){
  int i = blockIdx.x*4 + (threadIdx.x>>6), l = threadIdx.x&63;
  const float* r = W + (size_t)i*512;
  float s = 0.f;
  #pragma unroll
  for (int k=0;k<8;k++) s += r[l + 64*k]*v[l + 64*k];
  #pragma unroll
  for (int off=32; off; off>>=1) s += __shfl_xor(s, off);
  if (l==0) out[i] = s * SCALE;
}

// ---------------- two scaled dots (cb0, cb0_r) ----------------
__global__ __launch_bounds__(128) void dot2_k(const float* __restrict__ a0, const float* __restrict__ b0,
    const float* __restrict__ a1, const float* __restrict__ b1, float* __restrict__ out){
  int w = threadIdx.x>>6, l = threadIdx.x&63;
  const float* a = w ? a1 : a0;
  const float* b = w ? b1 : b0;
  float s = 0.f;
  #pragma unroll
  for (int k=0;k<8;k++) s += a[l + 64*k]*b[l + 64*k];
  #pragma unroll
  for (int off=32; off; off>>=1) s += __shfl_xor(s, off);
  if (l==0) out[w] = s * SCALE;
}

// ---------------- transpose + convert fp32 [512][512] -> bf16 [512][512]^T ----------------
__global__ __launch_bounds__(256) void tconv_k(const float* __restrict__ in, u16* __restrict__ out){
  __shared__ float t[32][33];
  int c0 = blockIdx.x*32, r0 = blockIdx.y*32;
  int cx = threadIdx.x&31, ry = threadIdx.x>>5;
  #pragma unroll
  for (int i=0;i<4;i++){ int r = ry + i*8; t[r][cx] = in[(size_t)(r0+r)*512 + c0+cx]; }
  __syncthreads();
  #pragma unroll
  for (int i=0;i<4;i++){ int r = ry + i*8; out[(size_t)(c0+r)*512 + r0+cx] = f2b(t[cx][r]); }
}

// ---------------- straight cast fp32 -> bf16 ----------------
__global__ __launch_bounds__(256) void conv_k(const float* __restrict__ in, u16* __restrict__ out){
  int i = blockIdx.x*256 + threadIdx.x;
  out[i] = f2b(in[i]);
}

// ---------------- memory init (fp32 + bf16 mirror) ----------------
__global__ __launch_bounds__(256) void meminit_k(const float* __restrict__ src,
    float* __restrict__ mem, u16* __restrict__ memh){
  int i = blockIdx.x*256 + threadIdx.x;
  float v = src[i & (SS*DM-1)];
  mem[i] = v;
  memh[i] = f2b(v);
}

// ---------------- mem = LN(0.9*mem + 0.1*w3) -> fp32 + bf16 mirror ----------------
__global__ __launch_bounds__(256) void mem_ln_k(float* __restrict__ mem, const float* __restrict__ w3,
    const float* __restrict__ g, const float* __restrict__ be, u16* __restrict__ memh){
  int row = blockIdx.x;
  int d = threadIdx.x;
  float* mrow = mem + (size_t)row*DM;
  const float* wrow = w3 + (size_t)row*DM;
  float x0 = 0.9f*mrow[d]     + 0.1f*wrow[d];
  float x1 = 0.9f*mrow[d+256] + 0.1f*wrow[d+256];
  float s1 = x0+x1, s2 = x0*x0 + x1*x1;
  s1 = wave_reduce_sum(s1); s2 = wave_reduce_sum(s2);
  __shared__ float r1[4], r2[4];
  int lane = d & 63, w = d>>6;
  if (lane==0){ r1[w]=s1; r2[w]=s2; }
  __syncthreads();
  float S1 = r1[0]+r1[1]+r1[2]+r1[3];
  float S2 = r2[0]+r2[1]+r2[2]+r2[3];
  float mu = S1 * (1.f/DM);
  float var = S2*(1.f/DM) - mu*mu;
  float rs = rsqrtf(var + 1e-5f);
  float y0 = (x0-mu)*rs*g[d] + be[d];
  float y1 = (x1-mu)*rs*g[d+256] + be[d+256];
  mrow[d] = y0; mrow[d+256] = y1;
  memh[(size_t)row*DM + d] = f2b(y0);
  memh[(size_t)row*DM + d+256] = f2b(y1);
}

// ---------------- masked token sum partials ----------------
__global__ __launch_bounds__(256) void tokpart_k(const u16* __restrict__ tok,
    const int* __restrict__ mask, float* __restrict__ tp){
  int b = blockIdx.x, sl = blockIdx.y, d = threadIdx.x;
  float s0=0.f, s1=0.f;
  for (int t = sl*128; t < sl*128+128; ++t){
    float m = (float)mask[b*TT + t];
    const u16* row = tok + ((size_t)(b*TT + t))*512;
    s0 += m*b2f(row[d]);
    s1 += m*b2f(row[d+256]);
  }
  tp[((size_t)(b*16 + sl))*512 + d] = s0;
  tp[((size_t)(b*16 + sl))*512 + d+256] = s1;
}

// ---------------- final: ctx = rws@rv ; fuse ; pool ; classify ----------------
__global__ __launch_bounds__(256) void final_k(const float* __restrict__ tp,
    const float* __restrict__ rws, const float* __restrict__ rv,
    const int* __restrict__ mask, const float* __restrict__ fuseW, const float* __restrict__ fuseb,
    const float* __restrict__ clsW, const float* __restrict__ clsb, float* __restrict__ out){
  int b = blockIdx.x, tid = threadIdx.x;
  __shared__ float cat[2*DM];
  __shared__ float pooled[DM];
  __shared__ float dred[4];
  float dn = 0.f;
  for (int t=tid; t<TT; t+=256) dn += (float)mask[b*TT+t];
  dn = wave_reduce_sum(dn);
  if ((tid&63)==0) dred[tid>>6]=dn;
  __syncthreads();
  float denom = dred[0]+dred[1]+dred[2]+dred[3];
  for (int d=tid; d<DM; d+=256){
    float ts = 0.f;
    for (int sl=0; sl<16; sl++) ts += tp[((size_t)(b*16+sl))*512 + d];
    cat[d] = ts;
    float c = 0.f;
    for (int s=0;s<SS;s++) c += rws[b*SS+s]*rv[((size_t)b*SS+s)*DM + d];
    cat[DM+d] = c;
  }
  __syncthreads();
  float dinv = 1.f/fmaxf(denom, 1.f);
  for (int d=tid; d<DM; d+=256){
    float acc = 0.f;
    for (int k=0;k<2*DM;k++) acc += cat[k]*fuseW[(size_t)k*DM + d];
    pooled[d] = (acc + denom*fuseb[d])*dinv;
  }
  __syncthreads();
  if (tid < 8){
    float acc=0.f;
    for (int d=0;d<DM;d++) acc += pooled[d]*clsW[d*8+tid];
    out[b*8+tid] = acc + clsb[tid];
  }
}

extern "C" void kernel_launch(void* const* d_in, const int* in_sizes, int n_in,
                              void* d_out, int out_size, void* d_ws, size_t ws_size,
                              hipStream_t stream){
  (void)in_sizes; (void)n_in; (void)out_size; (void)ws_size;
  const int*   ids   = (const int*)d_in[0];
  const int*   amask = (const int*)d_in[1];
  const float* temb  = (const float*)d_in[2];
  const float* pemb  = (const float*)d_in[3];
  const float* mem0  = (const float*)d_in[4];
  const float* qW=(const float*)d_in[5],  *qB=(const float*)d_in[6];
  const float* kW=(const float*)d_in[7],  *kB=(const float*)d_in[8];
  const float* vW=(const float*)d_in[9],  *vB=(const float*)d_in[10];
  const float* wrW=(const float*)d_in[11],*wrB=(const float*)d_in[12];
  const float* gtW=(const float*)d_in[13],*gtB=(const float*)d_in[14];
  const float* rqW=(const float*)d_in[15],*rqB=(const float*)d_in[16];
  const float* rkW=(const float*)d_in[17],*rkB=(const float*)d_in[18];
  const float* rvW=(const float*)d_in[19],*rvB=(const float*)d_in[20];
  const float* fW=(const float*)d_in[21], *fB=(const float*)d_in[22];
  const float* cW=(const float*)d_in[23], *cB=(const float*)d_in[24];
  const float* tg=(const float*)d_in[25], *tb=(const float*)d_in[26];
  const float* mg=(const float*)d_in[27], *mb=(const float*)d_in[28];

  // ---- workspace layout (~110 MB) ----
  char* p = (char*)d_ws;
  size_t off = 0;
  auto alloc = [&](size_t bytes)->char*{ char* r = p + off; off += (bytes + 255) & ~(size_t)255; return r; };
  u16*   tokens = (u16*)  alloc((size_t)BT*DM*2);        // 67.1 MB
  u16*   Pt     = (u16*)  alloc((size_t)BB*SS*DM*2);     // 2.1 MB
  u16*   BNDT   = (u16*)  alloc((size_t)BB*SS*TT*2);     // 8.4 MB
  float* cspart = (float*)alloc((size_t)BB*32*64*4);     // 0.26 MB
  float* wtpart = (float*)alloc((size_t)4*2048*512*4);   // 16.8 MB (hosts aliases below)
  u16*   t1h    = (u16*)  alloc((size_t)2048*512*2);
  u16*   t2h    = (u16*)  alloc((size_t)2048*512*2);
  u16*   zh     = (u16*)  alloc((size_t)2048*512*2);
  float* mem    = (float*)alloc((size_t)BB*SS*DM*4);
  u16*   memh   = (u16*)  alloc((size_t)BB*SS*DM*2);
  u16*   vWT    = (u16*)  alloc(512*512*2);
  u16*   wrWT   = (u16*)  alloc(512*512*2);
  u16*   gtWT   = (u16*)  alloc(512*512*2);
  u16*   rvWT   = (u16*)  alloc(512*512*2);
  u16*   WqkT   = (u16*)  alloc(512*512*2);
  u16*   WqkT_r = (u16*)  alloc(512*512*2);
  float* bq     = (float*)alloc(512*4);
  float* bq_r   = (float*)alloc(512*4);
  float* wcb    = (float*)alloc(512*4);
  float* wcb_r  = (float*)alloc(512*4);
  float* cb0s   = (float*)alloc(256);
  float* cbuf   = (float*)alloc(2048*4);
  float* slot   = (float*)alloc(2048*4);
  float* rr     = (float*)alloc(2048*4);
  float* raw    = (float*)alloc(2048*4);
  // aliases inside wtpart (liveness-disjoint):
  float* rv32   = wtpart;                       // read phase only
  float* tspart = wtpart + 1048576;             // read phase only
  float* gh32   = wtpart + 2097152;             // after wtred, before next wt
  u16*   qWb    = (u16*)((char*)wtpart + 12582912);  // precompute only
  u16*   kWb    = qWb + 512*512;
  u16*   rqWb   = kWb + 512*512;
  u16*   rkWb   = rqWb + 512*512;

  // ---- precompute ----
  conv_k<<<1024, 256, 0, stream>>>(qW, qWb);
  conv_k<<<1024, 256, 0, stream>>>(kW, kWb);
  conv_k<<<1024, 256, 0, stream>>>(rqW, rqWb);
  conv_k<<<1024, 256, 0, stream>>>(rkW, rkWb);
  tconv_k<<<dim3(16,16), 256, 0, stream>>>(vW, vWT);
  tconv_k<<<dim3(16,16), 256, 0, stream>>>(wrW, wrWT);
  tconv_k<<<dim3(16,16), 256, 0, stream>>>(gtW, gtWT);
  tconv_k<<<dim3(16,16), 256, 0, stream>>>(rvW, rvWT);
  ntgemm_k<4><<<dim3(16,8), 128, 0, stream>>>(qWb, kWb, nullptr, nullptr, nullptr, WqkT, SCALE);
  ntgemm_k<4><<<dim3(16,8), 128, 0, stream>>>(rqWb, rkWb, nullptr, nullptr, nullptr, WqkT_r, SCALE);
  matvec_k<<<128, 256, 0, stream>>>(qW, kB, bq);
  matvec_k<<<128, 256, 0, stream>>>(rqW, rkB, bq_r);
  matvec_k<<<128, 256, 0, stream>>>(kW, qB, wcb);
  matvec_k<<<128, 256, 0, stream>>>(rkW, rqB, wcb_r);
  dot2_k<<<1, 128, 0, stream>>>(kB, qB, rkB, rqB, cb0s);
  embed_ln_k<<<BT, 256, 0, stream>>>(ids, temb, pemb, tg, tb, tokens);
  meminit_k<<<(BB*SS*DM)/256, 256, 0, stream>>>(mem0, mem, memh);

  // ---- recurrent steps ----
  for (int step=0; step<NSTEPS; ++step){
    ntgemm_k<0><<<dim3(64,8), 128, 0, stream>>>(memh, WqkT, bq, nullptr, nullptr, Pt, 0.f);
    cb_k<<<512, 256, 0, stream>>>(mem, wcb, cb0s, cbuf);
    bind_k<<<dim3(32,32), 256, 0, stream>>>(tokens, Pt, cbuf, amask, BNDT, cspart);
    csred_k<<<32, 64, 0, stream>>>(cspart, slot, rr, raw);
    wt_k<<<dim3(4,32,4), 256, 0, stream>>>(BNDT, tokens, wtpart);
    wtred_k<<<4096, 256, 0, stream>>>(wtpart, slot, t1h);
    ntgemm_k<1><<<dim3(64,8), 128, 0, stream>>>(t1h, vWT, vB, nullptr, rr, t2h, 0.f);
    ntgemm_k<0><<<dim3(64,8), 128, 0, stream>>>(t2h, wrWT, wrB, nullptr, nullptr, zh, 0.f);
    ntgemm_k<2><<<dim3(64,8), 128, 0, stream>>>(zh, gtWT, gtB, zh, nullptr, gh32, 0.f);
    mem_ln_k<<<BB*SS, 256, 0, stream>>>(mem, gh32, mg, mb, memh);
  }

  // ---- read phase ----
  ntgemm_k<0><<<dim3(64,8), 128, 0, stream>>>(memh, WqkT_r, bq_r, nullptr, nullptr, Pt, 0.f);
  cb_k<<<512, 256, 0, stream>>>(mem, wcb_r, cb0s+1, cbuf);
  bind_k<<<dim3(32,32), 256, 0, stream>>>(tokens, Pt, cbuf, amask, BNDT, cspart);
  csred_k<<<32, 64, 0, stream>>>(cspart, slot, rr, raw);
  ntgemm_k<3><<<dim3(64,8), 128, 0, stream>>>(memh, rvWT, rvB, nullptr, nullptr, rv32, 0.f);
  tokpart_k<<<dim3(32,16), 256, 0, stream>>>(tokens, amask, tspart);
  final_k<<<32, 256, 0, stream>>>(tspart, raw, rv32, amask, fW, fB, cW, cB, (float*)d_out);
}

// Round 6
// 867.963 us; speedup vs baseline: 3.1443x; 1.0540x over previous
//
#include <hip/hip_runtime.h>
#include <hip/hip_bf16.h>
#include <math.h>

#define BB 32
#define TT 2048
#define DM 512
#define SS 64
#define BT (BB*TT)
#define NSTEPS 4
#define SCALE 0.044194173824159216f

typedef unsigned short u16;
typedef __attribute__((ext_vector_type(8))) short s16x8;
typedef __attribute__((ext_vector_type(4))) float f32x4;

__device__ __forceinline__ u16 f2b(float x){
  __hip_bfloat16 h = __float2bfloat16(x);
  return *reinterpret_cast<u16*>(&h);
}
__device__ __forceinline__ float b2f(u16 u){
  __hip_bfloat16 h;
  *reinterpret_cast<u16*>(&h) = u;
  return __bfloat162float(h);
}

static __device__ __forceinline__ float wave_reduce_sum(float v){
  #pragma unroll
  for (int off=32; off; off>>=1) v += __shfl_down(v, off);
  return v;
}

// ---------------- embedding + token LN (bf16 out) ----------------
__global__ __launch_bounds__(256) void embed_ln_k(const int* __restrict__ ids,
    const float* __restrict__ temb, const float* __restrict__ pemb,
    const float* __restrict__ g, const float* __restrict__ be, u16* __restrict__ out){
  int row = blockIdx.x;
  int t = row & (TT-1);
  int id = ids[row];
  int d = threadIdx.x;
  const float* te = temb + (size_t)id*DM;
  const float* pe = pemb + (size_t)t*DM;
  float x0 = te[d] + pe[d];
  float x1 = te[d+256] + pe[d+256];
  float s1 = x0+x1, s2 = x0*x0 + x1*x1;
  s1 = wave_reduce_sum(s1); s2 = wave_reduce_sum(s2);
  __shared__ float r1[4], r2[4];
  int lane = d & 63, w = d>>6;
  if (lane==0){ r1[w]=s1; r2[w]=s2; }
  __syncthreads();
  float S1 = r1[0]+r1[1]+r1[2]+r1[3];
  float S2 = r2[0]+r2[1]+r2[2]+r2[3];
  float mu = S1 * (1.f/DM);
  float var = S2*(1.f/DM) - mu*mu;
  float rs = rsqrtf(var + 1e-5f);
  u16* orow = out + (size_t)row*DM;
  orow[d]     = f2b((x0-mu)*rs*g[d] + be[d]);
  orow[d+256] = f2b((x1-mu)*rs*g[d+256] + be[d+256]);
}

// ---------------- generic NT bf16 MFMA gemm: C[M][512] = A[M][512] @ Bm[512][512]^T ----------------
// EPI: 0 = bf16(acc+bias[n]) ; 1 = bf16(acc + rowv[m]*bias[n]) ;
//      2 = f32( b2f(mul[m,n]) * sigmoid(acc+bias[n]) ) ; 3 = f32(acc+bias[n]) ; 4 = bf16(acc*scalep)
template<int EPI>
__global__ __launch_bounds__(128) void ntgemm_k(const u16* __restrict__ A,
    const u16* __restrict__ Bm, const float* __restrict__ bias,
    const u16* __restrict__ mulb, const float* __restrict__ rowv,
    void* __restrict__ Cout, float scalep){
  int m0 = blockIdx.x*32 + (threadIdx.x>>6)*16;
  int n0 = blockIdx.y*64;
  int l = threadIdx.x & 63;
  int lr = l & 15, lk = (l>>4)*8;
  const u16* Arow = A + (size_t)(m0 + lr)*512 + lk;
  const u16* B0   = Bm + (size_t)(n0 + lr)*512 + lk;
  f32x4 acc[4] = {};
  #pragma unroll
  for (int k0=0;k0<512;k0+=32){
    s16x8 a = *(const s16x8*)(Arow + k0);
    #pragma unroll
    for (int j=0;j<4;j++){
      s16x8 b = *(const s16x8*)(B0 + (size_t)j*16*512 + k0);
      acc[j] = __builtin_amdgcn_mfma_f32_16x16x32_bf16(a, b, acc[j], 0,0,0);
    }
  }
  int mbase = m0 + (l>>4)*4;
  #pragma unroll
  for (int j=0;j<4;j++){
    int n = n0 + j*16 + lr;
    #pragma unroll
    for (int r=0;r<4;r++){
      int m = mbase + r;
      float v = acc[j][r];
      if (EPI==0){ ((u16*)Cout)[(size_t)m*512 + n] = f2b(v + bias[n]); }
      if (EPI==1){ ((u16*)Cout)[(size_t)m*512 + n] = f2b(v + rowv[m]*bias[n]); }
      if (EPI==2){
        float z = v + bias[n];
        float sg = 1.f/(1.f + expf(-z));
        ((float*)Cout)[(size_t)m*512 + n] = b2f(mulb[(size_t)m*512 + n]) * sg;
      }
      if (EPI==3){ ((float*)Cout)[(size_t)m*512 + n] = v + bias[n]; }
      if (EPI==4){ ((u16*)Cout)[(size_t)m*512 + n] = f2b(v * scalep); }
    }
  }
}

// ---------------- fused scores + top8 softmax binding + colsum partial ----------------
__global__ __launch_bounds__(256) void bind_k(const u16* __restrict__ tok,
    const u16* __restrict__ Pt, const float* __restrict__ cbuf, const int* __restrict__ mask,
    u16* __restrict__ BNDT, float* __restrict__ cspart){
  int b = blockIdx.y, t0 = blockIdx.x*64;
  int tid = threadIdx.x, w = tid>>6, l = tid&63;
  int lr = l&15, g = l>>4, lk = g*8;
  __shared__ u16 bt[64][72];
  __shared__ float cs[16][64];
  const u16* Arow = tok + ((size_t)(b*TT + t0 + 16*w + lr))*512 + lk;
  const u16* Brow = Pt + ((size_t)(b*SS + lr))*512 + lk;
  f32x4 acc[4] = {};
  #pragma unroll
  for (int k0=0;k0<512;k0+=32){
    s16x8 a = *(const s16x8*)(Arow + k0);
    #pragma unroll
    for (int j=0;j<4;j++){
      s16x8 bb = *(const s16x8*)(Brow + (size_t)j*16*512 + k0);
      acc[j] = __builtin_amdgcn_mfma_f32_16x16x32_bf16(a, bb, acc[j], 0,0,0);
    }
  }
  float cbv[4];
  #pragma unroll
  for (int j=0;j<4;j++) cbv[j] = cbuf[b*SS + 16*j + lr];
  float cssum[4] = {0.f,0.f,0.f,0.f};
  #pragma unroll
  for (int r=0;r<4;r++){
    int row = 16*w + 4*g + r;
    float sv[4], work[4];
    #pragma unroll
    for (int j=0;j<4;j++){
      float x = acc[j][r] + cbv[j];
      x = fminf(fmaxf(x, -10.f), 10.f);
      sv[j] = x; work[j] = x;
    }
    bool sel[4] = {false,false,false,false};
    float topmax = 0.f;
    #pragma unroll
    for (int it=0; it<8; ++it){
      float lv = work[0]; int lc = lr;
      #pragma unroll
      for (int j=1;j<4;j++){ if (work[j] > lv){ lv = work[j]; lc = 16*j + lr; } }
      #pragma unroll
      for (int off=1; off<16; off<<=1){
        float ov = __shfl_xor(lv, off);
        int oc = __shfl_xor(lc, off);
        if (ov > lv || (ov == lv && oc < lc)){ lv = ov; lc = oc; }
      }
      if (it==0) topmax = lv;
      if ((lc & 15) == lr){ int jj = lc >> 4; sel[jj] = true; work[jj] = -INFINITY; }
    }
    float e[4], tot = 0.f;
    #pragma unroll
    for (int j=0;j<4;j++){ e[j] = sel[j] ? expf(sv[j]-topmax) : 0.f; tot += e[j]; }
    #pragma unroll
    for (int off=1; off<16; off<<=1) tot += __shfl_xor(tot, off);
    int mv = mask[b*TT + t0 + row];
    float inv = mv ? 1.f/tot : 0.f;
    #pragma unroll
    for (int j=0;j<4;j++){
      float wv = e[j]*inv;
      bt[16*j + lr][row] = f2b(wv);
      cssum[j] += wv;
    }
  }
  #pragma unroll
  for (int j=0;j<4;j++) cs[w*4+g][16*j+lr] = cssum[j];
  __syncthreads();
  if (tid < 64){
    float s = 0.f;
    #pragma unroll
    for (int k=0;k<16;k++) s += cs[k][tid];
    cspart[((size_t)b*32 + blockIdx.x)*64 + tid] = s;
  }
  int s = tid>>2, ch = (tid&3)*16;
  u16* dst = BNDT + ((size_t)(b*SS + s))*TT + t0 + ch;
  s16x8 w0 = *(const s16x8*)&bt[s][ch];
  s16x8 w1 = *(const s16x8*)&bt[s][ch+8];
  *(s16x8*)dst = w0;
  *(s16x8*)(dst+8) = w1;
}

// ---------------- colsum reduce: slot (clamped), rr, raw ----------------
__global__ __launch_bounds__(64) void csred_k(const float* __restrict__ cspart,
    float* __restrict__ slot, float* __restrict__ rr, float* __restrict__ raw){
  int b = blockIdx.x, s = threadIdx.x;
  float t = 0.f;
  for (int k=0;k<32;k++) t += cspart[((size_t)b*32 + k)*64 + s];
  raw[b*SS+s] = t;
  float sl = fmaxf(t, 1e-6f);
  slot[b*SS+s] = sl;
  rr[b*SS+s] = t/sl;
}

// ---------------- wt: part[ks][b*64+s][d] = sum_{t in slice} BNDT[b,s,t]*tok[b,t,d] ----------------
__global__ __launch_bounds__(256) void wt_k(const u16* __restrict__ BNDT,
    const u16* __restrict__ tok, float* __restrict__ part){
  int dgrp = blockIdx.x, b = blockIdx.y, ks = blockIdx.z;
  int tid = threadIdx.x, w = tid>>6, l = tid&63;
  int lr = l&15, lk = (l>>4)*8;
  __shared__ u16 tk[128][72];
  f32x4 acc[8] = {};
  int trow = tid>>2, dseg = (tid&3)*32;
  const u16* tokbase = tok + ((size_t)b*TT)*512 + dgrp*128;
  const u16* Abase = BNDT + ((size_t)(b*SS + 16*w + lr))*TT;
  for (int chunk=0; chunk<8; ++chunk){
    int tb = ks*512 + chunk*64;
    const u16* src = tokbase + (size_t)(tb + trow)*512 + dseg;
    s16x8 v0 = *(const s16x8*)(src);
    s16x8 v1 = *(const s16x8*)(src+8);
    s16x8 v2 = *(const s16x8*)(src+16);
    s16x8 v3 = *(const s16x8*)(src+24);
    #pragma unroll
    for (int e=0;e<8;e++){
      int d0 = dseg+e, d1 = dseg+8+e, d2 = dseg+16+e, d3 = dseg+24+e;
      tk[d0][(trow + 8*((d0>>5)&3)) & 63] = (u16)v0[e];
      tk[d1][(trow + 8*((d1>>5)&3)) & 63] = (u16)v1[e];
      tk[d2][(trow + 8*((d2>>5)&3)) & 63] = (u16)v2[e];
      tk[d3][(trow + 8*((d3>>5)&3)) & 63] = (u16)v3[e];
    }
    __syncthreads();
    #pragma unroll
    for (int kst=0;kst<2;kst++){
      s16x8 a = *(const s16x8*)(Abase + tb + kst*32 + lk);
      #pragma unroll
      for (int nt=0;nt<8;nt++){
        int dd = nt*16 + lr;
        int cb2 = (kst*32 + lk + 8*((dd>>5)&3)) & 63;
        s16x8 bb = *(const s16x8*)&tk[dd][cb2];
        acc[nt] = __builtin_amdgcn_mfma_f32_16x16x32_bf16(a, bb, acc[nt], 0,0,0);
      }
    }
    __syncthreads();
  }
  float* dst = part + (size_t)ks*2048*512 + ((size_t)(b*SS))*512 + dgrp*128;
  #pragma unroll
  for (int nt=0;nt<8;nt++){
    int d = nt*16 + lr;
    #pragma unroll
    for (int r=0;r<4;r++){
      int s = 16*w + (l>>4)*4 + r;
      dst[(size_t)s*512 + d] = acc[nt][r];
    }
  }
}

// ---------------- wt reduce + /slot -> bf16 ----------------
__global__ __launch_bounds__(256) void wtred_k(const float* __restrict__ part,
    const float* __restrict__ slot, u16* __restrict__ t1h){
  int i = blockIdx.x*256 + threadIdx.x;
  int row = i>>9;
  float v = part[i] + part[i + 2048*512] + part[i + 2*2048*512] + part[i + 3*2048*512];
  t1h[i] = f2b(v / slot[row]);
}

// ---------------- cb[row] = dot(mem[row,:], wcb) + cb0 ----------------
__global__ __launch_bounds__(256) void cb_k(const float* __restrict__ mem,
    const float* __restrict__ wcb, const float* __restrict__ cb0p, float* __restrict__ cb){
  int row = blockIdx.x*4 + (threadIdx.x>>6), l = threadIdx.x&63;
  const float* r = mem + (size_t)row*512;
  float s = 0.f;
  #pragma unroll
  for (int k=0;k<8;k++) s += r[l + 64*k]*wcb[l + 64*k];
  #pragma unroll
  for (int off=32; off; off>>=1) s += __shfl_xor(s, off);
  if (l==0) cb[row] = s + cb0p[0];
}

// ---------------- matvec: out[i] = scale * dot(W[i,:], v) ----------------
__global__ __launch_bounds__(256) void matvec_k(const float* __restrict__ W,
    const float* __restrict__ v, float* __restrict__ out){
  int i = blockIdx.x*4 + (threadIdx.x>>6), l = threadIdx.x&63;
  const float* r = W + (size_t)i*512;
  float s = 0.f;
  #pragma unroll
  for (int k=0;k<8;k++) s += r[l + 64*k]*v[l + 64*k];
  #pragma unroll
  for (int off=32; off; off>>=1) s += __shfl_xor(s, off);
  if (l==0) out[i] = s * SCALE;
}

// ---------------- two scaled dots (cb0, cb0_r) ----------------
__global__ __launch_bounds__(128) void dot2_k(const float* __restrict__ a0, const float* __restrict__ b0,
    const float* __restrict__ a1, const float* __restrict__ b1, float* __restrict__ out){
  int w = threadIdx.x>>6, l = threadIdx.x&63;
  const float* a = w ? a1 : a0;
  const float* b = w ? b1 : b0;
  float s = 0.f;
  #pragma unroll
  for (int k=0;k<8;k++) s += a[l + 64*k]*b[l + 64*k];
  #pragma unroll
  for (int off=32; off; off>>=1) s += __shfl_xor(s, off);
  if (l==0) out[w] = s * SCALE;
}

// ---------------- transpose + convert fp32 [512][512] -> bf16 [512][512]^T ----------------
__global__ __launch_bounds__(256) void tconv_k(const float* __restrict__ in, u16* __restrict__ out){
  __shared__ float t[32][33];
  int c0 = blockIdx.x*32, r0 = blockIdx.y*32;
  int cx = threadIdx.x&31, ry = threadIdx.x>>5;
  #pragma unroll
  for (int i=0;i<4;i++){ int r = ry + i*8; t[r][cx] = in[(size_t)(r0+r)*512 + c0+cx]; }
  __syncthreads();
  #pragma unroll
  for (int i=0;i<4;i++){ int r = ry + i*8; out[(size_t)(c0+r)*512 + r0+cx] = f2b(t[cx][r]); }
}

// ---------------- straight cast fp32 -> bf16 ----------------
__global__ __launch_bounds__(256) void conv_k(const float* __restrict__ in, u16* __restrict__ out){
  int i = blockIdx.x*256 + threadIdx.x;
  out[i] = f2b(in[i]);
}

// ---------------- memory init (fp32 + bf16 mirror) ----------------
__global__ __launch_bounds__(256) void meminit_k(const float* __restrict__ src,
    float* __restrict__ mem, u16* __restrict__ memh){
  int i = blockIdx.x*256 + threadIdx.x;
  float v = src[i & (SS*DM-1)];
  mem[i] = v;
  memh[i] = f2b(v);
}

// ---------------- mem = LN(0.9*mem + 0.1*w3) -> fp32 + bf16 mirror ----------------
__global__ __launch_bounds__(256) void mem_ln_k(float* __restrict__ mem, const float* __restrict__ w3,
    const float* __restrict__ g, const float* __restrict__ be, u16* __restrict__ memh){
  int row = blockIdx.x;
  int d = threadIdx.x;
  float* mrow = mem + (size_t)row*DM;
  const float* wrow = w3 + (size_t)row*DM;
  float x0 = 0.9f*mrow[d]     + 0.1f*wrow[d];
  float x1 = 0.9f*mrow[d+256] + 0.1f*wrow[d+256];
  float s1 = x0+x1, s2 = x0*x0 + x1*x1;
  s1 = wave_reduce_sum(s1); s2 = wave_reduce_sum(s2);
  __shared__ float r1[4], r2[4];
  int lane = d & 63, w = d>>6;
  if (lane==0){ r1[w]=s1; r2[w]=s2; }
  __syncthreads();
  float S1 = r1[0]+r1[1]+r1[2]+r1[3];
  float S2 = r2[0]+r2[1]+r2[2]+r2[3];
  float mu = S1 * (1.f/DM);
  float var = S2*(1.f/DM) - mu*mu;
  float rs = rsqrtf(var + 1e-5f);
  float y0 = (x0-mu)*rs*g[d] + be[d];
  float y1 = (x1-mu)*rs*g[d+256] + be[d+256];
  mrow[d] = y0; mrow[d+256] = y1;
  memh[(size_t)row*DM + d] = f2b(y0);
  memh[(size_t)row*DM + d+256] = f2b(y1);
}

// ---------------- masked token sum partials (vectorized, per-wave slices) ----------------
// tp[(b*64 + sl*4 + w)][d] = sum over wave-w's t rows in slice sl
__global__ __launch_bounds__(256) void tokpart_k(const u16* __restrict__ tok,
    const int* __restrict__ mask, float* __restrict__ tp){
  int b = blockIdx.x, sl = blockIdx.y;
  int w = threadIdx.x>>6, l = threadIdx.x&63;
  float acc[8] = {};
  #pragma unroll 4
  for (int i=0;i<32;i++){
    int t = sl*128 + w + 4*i;
    float m = (float)mask[b*TT + t];
    s16x8 v = *(const s16x8*)(tok + ((size_t)(b*TT + t))*512 + l*8);
    #pragma unroll
    for (int e=0;e<8;e++) acc[e] += m*b2f((u16)v[e]);
  }
  float* dst = tp + ((size_t)(b*64 + sl*4 + w))*512 + l*8;
  #pragma unroll
  for (int e=0;e<8;e++) dst[e] = acc[e];
}

// ---------------- catden: cat[b][1024] = [tok_sum, ctx], denom[b] ----------------
__global__ __launch_bounds__(256) void catden_k(const float* __restrict__ tp,
    const float* __restrict__ rws, const float* __restrict__ rv,
    const int* __restrict__ mask, float* __restrict__ cat, float* __restrict__ denomv){
  int b = blockIdx.x, tid = threadIdx.x;
  float dn = 0.f;
  for (int t=tid; t<TT; t+=256) dn += (float)mask[b*TT+t];
  dn = wave_reduce_sum(dn);
  __shared__ float dred[4];
  if ((tid&63)==0) dred[tid>>6]=dn;
  #pragma unroll
  for (int it=0; it<2; ++it){
    int d = tid + it*256;
    float ts = 0.f;
    for (int k=0;k<64;k++) ts += tp[((size_t)(b*64+k))*512 + d];
    cat[(size_t)b*1024 + d] = ts;
    float c = 0.f;
    for (int s=0;s<SS;s++) c += rws[b*SS+s]*rv[((size_t)b*SS+s)*DM + d];
    cat[(size_t)b*1024 + 512 + d] = c;
  }
  __syncthreads();
  if (tid==0) denomv[b] = dred[0]+dred[1]+dred[2]+dred[3];
}

// ---------------- fuse: pooled[b][n0..n0+64] ----------------
__global__ __launch_bounds__(256) void fuse_k(const float* __restrict__ cat,
    const float* __restrict__ denomv, const float* __restrict__ fuseW,
    const float* __restrict__ fuseb, float* __restrict__ pooled){
  int b = blockIdx.x, n0 = blockIdx.y*64;
  int l = threadIdx.x&63, kc = threadIdx.x>>6;
  int n = n0 + l;
  float acc = 0.f;
  const float* crow = cat + (size_t)b*1024;
  for (int k=kc*256; k<kc*256+256; ++k)
    acc += crow[k]*fuseW[(size_t)k*512 + n];
  __shared__ float red[4][64];
  red[kc][l] = acc;
  __syncthreads();
  if (kc==0){
    float denom = denomv[b];
    float tot = red[0][l]+red[1][l]+red[2][l]+red[3][l];
    pooled[(size_t)b*512 + n] = (tot + denom*fuseb[n]) / fmaxf(denom, 1.f);
  }
}

// ---------------- cls: out[b][8] ----------------
__global__ __launch_bounds__(256) void cls_k(const float* __restrict__ pooled,
    const float* __restrict__ clsW, const float* __restrict__ clsb, float* __restrict__ out){
  int b = blockIdx.x;
  int c = threadIdx.x&7, kc = threadIdx.x>>3;  // 32 chunks of 16 d
  float acc = 0.f;
  const float* prow = pooled + (size_t)b*512;
  for (int d=kc*16; d<kc*16+16; ++d) acc += prow[d]*clsW[d*8+c];
  __shared__ float red[32][8];
  red[kc][c] = acc;
  __syncthreads();
  if (threadIdx.x < 8){
    float tot = 0.f;
    #pragma unroll
    for (int k=0;k<32;k++) tot += red[k][threadIdx.x];
    out[b*8 + threadIdx.x] = tot + clsb[threadIdx.x];
  }
}

extern "C" void kernel_launch(void* const* d_in, const int* in_sizes, int n_in,
                              void* d_out, int out_size, void* d_ws, size_t ws_size,
                              hipStream_t stream){
  (void)in_sizes; (void)n_in; (void)out_size; (void)ws_size;
  const int*   ids   = (const int*)d_in[0];
  const int*   amask = (const int*)d_in[1];
  const float* temb  = (const float*)d_in[2];
  const float* pemb  = (const float*)d_in[3];
  const float* mem0  = (const float*)d_in[4];
  const float* qW=(const float*)d_in[5],  *qB=(const float*)d_in[6];
  const float* kW=(const float*)d_in[7],  *kB=(const float*)d_in[8];
  const float* vW=(const float*)d_in[9],  *vB=(const float*)d_in[10];
  const float* wrW=(const float*)d_in[11],*wrB=(const float*)d_in[12];
  const float* gtW=(const float*)d_in[13],*gtB=(const float*)d_in[14];
  const float* rqW=(const float*)d_in[15],*rqB=(const float*)d_in[16];
  const float* rkW=(const float*)d_in[17],*rkB=(const float*)d_in[18];
  const float* rvW=(const float*)d_in[19],*rvB=(const float*)d_in[20];
  const float* fW=(const float*)d_in[21], *fB=(const float*)d_in[22];
  const float* cW=(const float*)d_in[23], *cB=(const float*)d_in[24];
  const float* tg=(const float*)d_in[25], *tb=(const float*)d_in[26];
  const float* mg=(const float*)d_in[27], *mb=(const float*)d_in[28];

  // ---- workspace layout (~110 MB) ----
  char* p = (char*)d_ws;
  size_t off = 0;
  auto alloc = [&](size_t bytes)->char*{ char* r = p + off; off += (bytes + 255) & ~(size_t)255; return r; };
  u16*   tokens = (u16*)  alloc((size_t)BT*DM*2);        // 67.1 MB
  u16*   Pt     = (u16*)  alloc((size_t)BB*SS*DM*2);     // 2.1 MB
  u16*   BNDT   = (u16*)  alloc((size_t)BB*SS*TT*2);     // 8.4 MB
  float* cspart = (float*)alloc((size_t)BB*32*64*4);     // 0.26 MB
  float* wtpart = (float*)alloc((size_t)4*2048*512*4);   // 16.8 MB (hosts aliases below)
  u16*   t1h    = (u16*)  alloc((size_t)2048*512*2);
  u16*   t2h    = (u16*)  alloc((size_t)2048*512*2);
  u16*   zh     = (u16*)  alloc((size_t)2048*512*2);
  float* mem    = (float*)alloc((size_t)BB*SS*DM*4);
  u16*   memh   = (u16*)  alloc((size_t)BB*SS*DM*2);
  u16*   vWT    = (u16*)  alloc(512*512*2);
  u16*   wrWT   = (u16*)  alloc(512*512*2);
  u16*   gtWT   = (u16*)  alloc(512*512*2);
  u16*   rvWT   = (u16*)  alloc(512*512*2);
  u16*   WqkT   = (u16*)  alloc(512*512*2);
  u16*   WqkT_r = (u16*)  alloc(512*512*2);
  float* bq     = (float*)alloc(512*4);
  float* bq_r   = (float*)alloc(512*4);
  float* wcb    = (float*)alloc(512*4);
  float* wcb_r  = (float*)alloc(512*4);
  float* cb0s   = (float*)alloc(256);
  float* cbuf   = (float*)alloc(2048*4);
  float* slot   = (float*)alloc(2048*4);
  float* rr     = (float*)alloc(2048*4);
  float* raw    = (float*)alloc(2048*4);
  float* catbuf = (float*)alloc((size_t)BB*1024*4);
  float* denomv = (float*)alloc(BB*4);
  float* pooled = (float*)alloc((size_t)BB*512*4);
  // aliases inside wtpart (liveness-disjoint):
  float* rv32   = wtpart;                       // read phase only (4 MB)
  float* tspart = wtpart + 1048576;             // read phase only (4 MB: 32*64*512)
  float* gh32   = wtpart + 2097152;             // after wtred, before next wt (4 MB)
  u16*   qWb    = (u16*)((char*)wtpart + 12582912);  // precompute only
  u16*   kWb    = qWb + 512*512;
  u16*   rqWb   = kWb + 512*512;
  u16*   rkWb   = rqWb + 512*512;

  // ---- precompute ----
  conv_k<<<1024, 256, 0, stream>>>(qW, qWb);
  conv_k<<<1024, 256, 0, stream>>>(kW, kWb);
  conv_k<<<1024, 256, 0, stream>>>(rqW, rqWb);
  conv_k<<<1024, 256, 0, stream>>>(rkW, rkWb);
  tconv_k<<<dim3(16,16), 256, 0, stream>>>(vW, vWT);
  tconv_k<<<dim3(16,16), 256, 0, stream>>>(wrW, wrWT);
  tconv_k<<<dim3(16,16), 256, 0, stream>>>(gtW, gtWT);
  tconv_k<<<dim3(16,16), 256, 0, stream>>>(rvW, rvWT);
  ntgemm_k<4><<<dim3(16,8), 128, 0, stream>>>(qWb, kWb, nullptr, nullptr, nullptr, WqkT, SCALE);
  ntgemm_k<4><<<dim3(16,8), 128, 0, stream>>>(rqWb, rkWb, nullptr, nullptr, nullptr, WqkT_r, SCALE);
  matvec_k<<<128, 256, 0, stream>>>(qW, kB, bq);
  matvec_k<<<128, 256, 0, stream>>>(rqW, rkB, bq_r);
  matvec_k<<<128, 256, 0, stream>>>(kW, qB, wcb);
  matvec_k<<<128, 256, 0, stream>>>(rkW, rqB, wcb_r);
  dot2_k<<<1, 128, 0, stream>>>(kB, qB, rkB, rqB, cb0s);
  embed_ln_k<<<BT, 256, 0, stream>>>(ids, temb, pemb, tg, tb, tokens);
  meminit_k<<<(BB*SS*DM)/256, 256, 0, stream>>>(mem0, mem, memh);

  // ---- recurrent steps ----
  for (int step=0; step<NSTEPS; ++step){
    ntgemm_k<0><<<dim3(64,8), 128, 0, stream>>>(memh, WqkT, bq, nullptr, nullptr, Pt, 0.f);
    cb_k<<<512, 256, 0, stream>>>(mem, wcb, cb0s, cbuf);
    bind_k<<<dim3(32,32), 256, 0, stream>>>(tokens, Pt, cbuf, amask, BNDT, cspart);
    csred_k<<<32, 64, 0, stream>>>(cspart, slot, rr, raw);
    wt_k<<<dim3(4,32,4), 256, 0, stream>>>(BNDT, tokens, wtpart);
    wtred_k<<<4096, 256, 0, stream>>>(wtpart, slot, t1h);
    ntgemm_k<1><<<dim3(64,8), 128, 0, stream>>>(t1h, vWT, vB, nullptr, rr, t2h, 0.f);
    ntgemm_k<0><<<dim3(64,8), 128, 0, stream>>>(t2h, wrWT, wrB, nullptr, nullptr, zh, 0.f);
    ntgemm_k<2><<<dim3(64,8), 128, 0, stream>>>(zh, gtWT, gtB, zh, nullptr, gh32, 0.f);
    mem_ln_k<<<BB*SS, 256, 0, stream>>>(mem, gh32, mg, mb, memh);
  }

  // ---- read phase ----
  ntgemm_k<0><<<dim3(64,8), 128, 0, stream>>>(memh, WqkT_r, bq_r, nullptr, nullptr, Pt, 0.f);
  cb_k<<<512, 256, 0, stream>>>(mem, wcb_r, cb0s+1, cbuf);
  bind_k<<<dim3(32,32), 256, 0, stream>>>(tokens, Pt, cbuf, amask, BNDT, cspart);
  csred_k<<<32, 64, 0, stream>>>(cspart, slot, rr, raw);
  ntgemm_k<3><<<dim3(64,8), 128, 0, stream>>>(memh, rvWT, rvB, nullptr, nullptr, rv32, 0.f);
  tokpart_k<<<dim3(32,16), 256, 0, stream>>>(tokens, amask, tspart);
  catden_k<<<32, 256, 0, stream>>>(tspart, raw, rv32, amask, catbuf, denomv);
  fuse_k<<<dim3(32,8), 256, 0, stream>>>(catbuf, denomv, fW, fB, pooled);
  cls_k<<<32, 256, 0, stream>>>(pooled, cW, cB, (float*)d_out);
}

// Round 7
// 623.492 us; speedup vs baseline: 4.3772x; 1.3921x over previous
//
#include <hip/hip_runtime.h>
#include <hip/hip_bf16.h>
#include <math.h>

#define BB 32
#define TT 2048
#define DM 512
#define SS 64
#define BT (BB*TT)
#define NSTEPS 4
#define SCALE 0.044194173824159216f

typedef unsigned short u16;
typedef unsigned int u32;
typedef __attribute__((ext_vector_type(8))) short s16x8;
typedef __attribute__((ext_vector_type(4))) float f32x4;
typedef __attribute__((ext_vector_type(4))) unsigned u32x4;

__device__ __forceinline__ u16 f2b(float x){
  __hip_bfloat16 h = __float2bfloat16(x);
  return *reinterpret_cast<u16*>(&h);
}
__device__ __forceinline__ float b2f(u16 u){
  __hip_bfloat16 h;
  *reinterpret_cast<u16*>(&h) = u;
  return __bfloat162float(h);
}

static __device__ __forceinline__ float wave_reduce_sum(float v){
  #pragma unroll
  for (int off=32; off; off>>=1) v += __shfl_down(v, off);
  return v;
}

// ---------------- embedding + token LN (bf16 out) ----------------
__global__ __launch_bounds__(256) void embed_ln_k(const int* __restrict__ ids,
    const float* __restrict__ temb, const float* __restrict__ pemb,
    const float* __restrict__ g, const float* __restrict__ be, u16* __restrict__ out){
  int row = blockIdx.x;
  int t = row & (TT-1);
  int id = ids[row];
  int d = threadIdx.x;
  const float* te = temb + (size_t)id*DM;
  const float* pe = pemb + (size_t)t*DM;
  float x0 = te[d] + pe[d];
  float x1 = te[d+256] + pe[d+256];
  float s1 = x0+x1, s2 = x0*x0 + x1*x1;
  s1 = wave_reduce_sum(s1); s2 = wave_reduce_sum(s2);
  __shared__ float r1[4], r2[4];
  int lane = d & 63, w = d>>6;
  if (lane==0){ r1[w]=s1; r2[w]=s2; }
  __syncthreads();
  float S1 = r1[0]+r1[1]+r1[2]+r1[3];
  float S2 = r2[0]+r2[1]+r2[2]+r2[3];
  float mu = S1 * (1.f/DM);
  float var = S2*(1.f/DM) - mu*mu;
  float rs = rsqrtf(var + 1e-5f);
  u16* orow = out + (size_t)row*DM;
  orow[d]     = f2b((x0-mu)*rs*g[d] + be[d]);
  orow[d+256] = f2b((x1-mu)*rs*g[d+256] + be[d+256]);
}

// ---------------- generic NT bf16 MFMA gemm: C[M][512] = A[M][512] @ Bm[512][512]^T ----------------
// EPI: 0 = bf16(acc+bias[n]) ; 1 = bf16(acc + rowv[m]*bias[n]) ;
//      2 = f32( b2f(mul[m,n]) * sigmoid(acc+bias[n]) ) ; 3 = f32(acc+bias[n]) ; 4 = bf16(acc*scalep)
template<int EPI>
__global__ __launch_bounds__(128) void ntgemm_k(const u16* __restrict__ A,
    const u16* __restrict__ Bm, const float* __restrict__ bias,
    const u16* __restrict__ mulb, const float* __restrict__ rowv,
    void* __restrict__ Cout, float scalep){
  int m0 = blockIdx.x*32 + (threadIdx.x>>6)*16;
  int n0 = blockIdx.y*64;
  int l = threadIdx.x & 63;
  int lr = l & 15, lk = (l>>4)*8;
  const u16* Arow = A + (size_t)(m0 + lr)*512 + lk;
  const u16* B0   = Bm + (size_t)(n0 + lr)*512 + lk;
  f32x4 acc[4] = {};
  #pragma unroll
  for (int k0=0;k0<512;k0+=32){
    s16x8 a = *(const s16x8*)(Arow + k0);
    #pragma unroll
    for (int j=0;j<4;j++){
      s16x8 b = *(const s16x8*)(B0 + (size_t)j*16*512 + k0);
      acc[j] = __builtin_amdgcn_mfma_f32_16x16x32_bf16(a, b, acc[j], 0,0,0);
    }
  }
  int mbase = m0 + (l>>4)*4;
  #pragma unroll
  for (int j=0;j<4;j++){
    int n = n0 + j*16 + lr;
    #pragma unroll
    for (int r=0;r<4;r++){
      int m = mbase + r;
      float v = acc[j][r];
      if (EPI==0){ ((u16*)Cout)[(size_t)m*512 + n] = f2b(v + bias[n]); }
      if (EPI==1){ ((u16*)Cout)[(size_t)m*512 + n] = f2b(v + rowv[m]*bias[n]); }
      if (EPI==2){
        float z = v + bias[n];
        float sg = 1.f/(1.f + expf(-z));
        ((float*)Cout)[(size_t)m*512 + n] = b2f(mulb[(size_t)m*512 + n]) * sg;
      }
      if (EPI==3){ ((float*)Cout)[(size_t)m*512 + n] = v + bias[n]; }
      if (EPI==4){ ((u16*)Cout)[(size_t)m*512 + n] = f2b(v * scalep); }
    }
  }
}

// ---------------- fused scores + top8 softmax binding + colsum partial ----------------
// One wave per (64-t tile, b). Wave computes full 64x64 QK tile, transposes through
// LDS so each lane owns one t-row (64 scores in regs), then does per-lane top-8 via
// order-preserving u32 keys (26-bit value + 6-bit reverse index => unique keys,
// exact first-match removal), softmax, and transposes weights back for BNDT/cspart.
__global__ __launch_bounds__(64) void bind_k(const u16* __restrict__ tok,
    const u16* __restrict__ Pt, const float* __restrict__ cbuf, const int* __restrict__ mask,
    u16* __restrict__ BNDT, float* __restrict__ cspart){
  int b = blockIdx.y, t0 = blockIdx.x*64;
  int l = threadIdx.x;
  int lr = l&15, g = l>>4, lk = g*8;
  __shared__ float sc[64*66];
  __shared__ u16 bt[64*66];

  // ---- QK: full 64x64 tile in one wave (4 m-frags x 4 n-frags) ----
  const u16* Abase = tok + ((size_t)(b*TT + t0 + lr))*512 + lk;
  const u16* Bbase = Pt + ((size_t)(b*SS + lr))*512 + lk;
  f32x4 acc[4][4] = {};
  #pragma unroll
  for (int k0=0;k0<512;k0+=32){
    s16x8 a[4], bb[4];
    #pragma unroll
    for (int mi=0;mi<4;mi++) a[mi] = *(const s16x8*)(Abase + (size_t)mi*16*512 + k0);
    #pragma unroll
    for (int nj=0;nj<4;nj++) bb[nj] = *(const s16x8*)(Bbase + (size_t)nj*16*512 + k0);
    #pragma unroll
    for (int mi=0;mi<4;mi++)
      #pragma unroll
      for (int nj=0;nj<4;nj++)
        acc[mi][nj] = __builtin_amdgcn_mfma_f32_16x16x32_bf16(a[mi], bb[nj], acc[mi][nj], 0,0,0);
  }
  float cbv[4];
  #pragma unroll
  for (int nj=0;nj<4;nj++) cbv[nj] = cbuf[b*SS + 16*nj + lr];
  // clip + write to LDS: sc[t-row][s-col], stride 66 (2-way max on write & read)
  #pragma unroll
  for (int mi=0;mi<4;mi++)
    #pragma unroll
    for (int nj=0;nj<4;nj++)
      #pragma unroll
      for (int r=0;r<4;r++){
        float x = acc[mi][nj][r] + cbv[nj];
        x = fminf(fmaxf(x, -10.f), 10.f);
        sc[(16*mi + 4*g + r)*66 + 16*nj + lr] = x;
      }

  // ---- per-lane row: lane l owns row t0+l ----
  float sv[64];
  #pragma unroll
  for (int j=0;j<64;j++) sv[j] = sc[l*66 + j];

  // order-preserving keys: high 26 bits of flipped float + (63-j)
  u32 work[64];
  #pragma unroll
  for (int j=0;j<64;j++){
    u32 s = __float_as_uint(sv[j]);
    u32 o = s ^ ((u32)(((int)s) >> 31) | 0x80000000u);
    work[j] = (o & 0xFFFFFFC0u) | (u32)(63 - j);
  }
  u32 mtop = 0;
  #pragma unroll
  for (int it=0; it<8; ++it){
    u32 a[32];
    #pragma unroll
    for (int j=0;j<32;j++){ u32 x = work[2*j], y = work[2*j+1]; a[j] = x>y?x:y; }
    #pragma unroll
    for (int lvl=16; lvl>=1; lvl>>=1)
      #pragma unroll
      for (int j=0;j<lvl;j++){ u32 x = a[2*j], y = a[2*j+1]; a[j] = x>y?x:y; }
    u32 m = a[0];
    if (it==0) mtop = m;
    #pragma unroll
    for (int j=0;j<64;j++) work[j] = (work[j]==m) ? 0u : work[j];
  }
  // decode softmax shift T from top key bucket (any shift is exact for softmax)
  u32 ot = mtop & 0xFFFFFFC0u;
  u32 tb = (ot & 0x80000000u) ? (ot ^ 0x80000000u) : ~ot;
  float T = __uint_as_float(tb);

  float tot = 0.f;
  #pragma unroll
  for (int j=0;j<64;j++){
    float ej = (work[j]==0u) ? expf(sv[j]-T) : 0.f;
    sv[j] = ej;
    tot += ej;
  }
  int mv = mask[b*TT + t0 + l];
  float inv = mv ? 1.f/tot : 0.f;
  // transpose weights back: bt[s][t], stride 66 u16
  #pragma unroll
  for (int j=0;j<64;j++)
    bt[j*66 + l] = f2b(sv[j]*inv);

  // lane l reads s-row l (conflict-free), emits BNDT row + column-sum partial
  const u32* btw = (const u32*)bt;
  u32 rowbuf[32];
  float csum = 0.f;
  #pragma unroll
  for (int w=0;w<32;w++){
    u32 v = btw[l*33 + w];
    rowbuf[w] = v;
    csum += b2f((u16)(v & 0xFFFFu)) + b2f((u16)(v >> 16));
  }
  cspart[((size_t)b*32 + blockIdx.x)*64 + l] = csum;
  u16* dst = BNDT + ((size_t)(b*SS + l))*TT + t0;
  #pragma unroll
  for (int w8=0;w8<8;w8++){
    u32x4 v;
    v[0]=rowbuf[4*w8]; v[1]=rowbuf[4*w8+1]; v[2]=rowbuf[4*w8+2]; v[3]=rowbuf[4*w8+3];
    *(u32x4*)(dst + 8*w8) = v;
  }
}

// ---------------- colsum reduce: slot (clamped), rr, raw ----------------
__global__ __launch_bounds__(64) void csred_k(const float* __restrict__ cspart,
    float* __restrict__ slot, float* __restrict__ rr, float* __restrict__ raw){
  int b = blockIdx.x, s = threadIdx.x;
  float t = 0.f;
  for (int k=0;k<32;k++) t += cspart[((size_t)b*32 + k)*64 + s];
  raw[b*SS+s] = t;
  float sl = fmaxf(t, 1e-6f);
  slot[b*SS+s] = sl;
  rr[b*SS+s] = t/sl;
}

// ---------------- wt: part[ks][b*64+s][d] = sum_{t in slice} BNDT[b,s,t]*tok[b,t,d] ----------------
__global__ __launch_bounds__(256) void wt_k(const u16* __restrict__ BNDT,
    const u16* __restrict__ tok, float* __restrict__ part){
  int dgrp = blockIdx.x, b = blockIdx.y, ks = blockIdx.z;
  int tid = threadIdx.x, w = tid>>6, l = tid&63;
  int lr = l&15, lk = (l>>4)*8;
  __shared__ u16 tk[128][72];
  f32x4 acc[8] = {};
  int trow = tid>>2, dseg = (tid&3)*32;
  const u16* tokbase = tok + ((size_t)b*TT)*512 + dgrp*128;
  const u16* Abase = BNDT + ((size_t)(b*SS + 16*w + lr))*TT;
  for (int chunk=0; chunk<8; ++chunk){
    int tb = ks*512 + chunk*64;
    const u16* src = tokbase + (size_t)(tb + trow)*512 + dseg;
    s16x8 v0 = *(const s16x8*)(src);
    s16x8 v1 = *(const s16x8*)(src+8);
    s16x8 v2 = *(const s16x8*)(src+16);
    s16x8 v3 = *(const s16x8*)(src+24);
    #pragma unroll
    for (int e=0;e<8;e++){
      int d0 = dseg+e, d1 = dseg+8+e, d2 = dseg+16+e, d3 = dseg+24+e;
      tk[d0][(trow + 8*((d0>>5)&3)) & 63] = (u16)v0[e];
      tk[d1][(trow + 8*((d1>>5)&3)) & 63] = (u16)v1[e];
      tk[d2][(trow + 8*((d2>>5)&3)) & 63] = (u16)v2[e];
      tk[d3][(trow + 8*((d3>>5)&3)) & 63] = (u16)v3[e];
    }
    __syncthreads();
    #pragma unroll
    for (int kst=0;kst<2;kst++){
      s16x8 a = *(const s16x8*)(Abase + tb + kst*32 + lk);
      #pragma unroll
      for (int nt=0;nt<8;nt++){
        int dd = nt*16 + lr;
        int cb2 = (kst*32 + lk + 8*((dd>>5)&3)) & 63;
        s16x8 bb = *(const s16x8*)&tk[dd][cb2];
        acc[nt] = __builtin_amdgcn_mfma_f32_16x16x32_bf16(a, bb, acc[nt], 0,0,0);
      }
    }
    __syncthreads();
  }
  float* dst = part + (size_t)ks*2048*512 + ((size_t)(b*SS))*512 + dgrp*128;
  #pragma unroll
  for (int nt=0;nt<8;nt++){
    int d = nt*16 + lr;
    #pragma unroll
    for (int r=0;r<4;r++){
      int s = 16*w + (l>>4)*4 + r;
      dst[(size_t)s*512 + d] = acc[nt][r];
    }
  }
}

// ---------------- wt reduce + /slot -> bf16 ----------------
__global__ __launch_bounds__(256) void wtred_k(const float* __restrict__ part,
    const float* __restrict__ slot, u16* __restrict__ t1h){
  int i = blockIdx.x*256 + threadIdx.x;
  int row = i>>9;
  float v = part[i] + part[i + 2048*512] + part[i + 2*2048*512] + part[i + 3*2048*512];
  t1h[i] = f2b(v / slot[row]);
}

// ---------------- cb[row] = dot(mem[row,:], wcb) + cb0 ----------------
__global__ __launch_bounds__(256) void cb_k(const float* __restrict__ mem,
    const float* __restrict__ wcb, const float* __restrict__ cb0p, float* __restrict__ cb){
  int row = blockIdx.x*4 + (threadIdx.x>>6), l = threadIdx.x&63;
  const float* r = mem + (size_t)row*512;
  float s = 0.f;
  #pragma unroll
  for (int k=0;k<8;k++) s += r[l + 64*k]*wcb[l + 64*k];
  #pragma unroll
  for (int off=32; off; off>>=1) s += __shfl_xor(s, off);
  if (l==0) cb[row] = s + cb0p[0];
}

// ---------------- matvec: out[i] = scale * dot(W[i,:], v) ----------------
__global__ __launch_bounds__(256) void matvec_k(const float* __restrict__ W,
    const float* __restrict__ v, float* __restrict__ out){
  int i = blockIdx.x*4 + (threadIdx.x>>6), l = threadIdx.x&63;
  const float* r = W + (size_t)i*512;
  float s = 0.f;
  #pragma unroll
  for (int k=0;k<8;k++) s += r[l + 64*k]*v[l + 64*k];
  #pragma unroll
  for (int off=32; off; off>>=1) s += __shfl_xor(s, off);
  if (l==0) out[i] = s * SCALE;
}

// ---------------- two scaled dots (cb0, cb0_r) ----------------
__global__ __launch_bounds__(128) void dot2_k(const float* __restrict__ a0, const float* __restrict__ b0,
    const float* __restrict__ a1, const float* __restrict__ b1, float* __restrict__ out){
  int w = threadIdx.x>>6, l = threadIdx.x&63;
  const float* a = w ? a1 : a0;
  const float* b = w ? b1 : b0;
  float s = 0.f;
  #pragma unroll
  for (int k=0;k<8;k++) s += a[l + 64*k]*b[l + 64*k];
  #pragma unroll
  for (int off=32; off; off>>=1) s += __shfl_xor(s, off);
  if (l==0) out[w] = s * SCALE;
}

// ---------------- transpose + convert fp32 [512][512] -> bf16 [512][512]^T ----------------
__global__ __launch_bounds__(256) void tconv_k(const float* __restrict__ in, u16* __restrict__ out){
  __shared__ float t[32][33];
  int c0 = blockIdx.x*32, r0 = blockIdx.y*32;
  int cx = threadIdx.x&31, ry = threadIdx.x>>5;
  #pragma unroll
  for (int i=0;i<4;i++){ int r = ry + i*8; t[r][cx] = in[(size_t)(r0+r)*512 + c0+cx]; }
  __syncthreads();
  #pragma unroll
  for (int i=0;i<4;i++){ int r = ry + i*8; out[(size_t)(c0+r)*512 + r0+cx] = f2b(t[cx][r]); }
}

// ---------------- straight cast fp32 -> bf16 ----------------
__global__ __launch_bounds__(256) void conv_k(const float* __restrict__ in, u16* __restrict__ out){
  int i = blockIdx.x*256 + threadIdx.x;
  out[i] = f2b(in[i]);
}

// ---------------- memory init (fp32 + bf16 mirror) ----------------
__global__ __launch_bounds__(256) void meminit_k(const float* __restrict__ src,
    float* __restrict__ mem, u16* __restrict__ memh){
  int i = blockIdx.x*256 + threadIdx.x;
  float v = src[i & (SS*DM-1)];
  mem[i] = v;
  memh[i] = f2b(v);
}

// ---------------- mem = LN(0.9*mem + 0.1*w3) -> fp32 + bf16 mirror ----------------
__global__ __launch_bounds__(256) void mem_ln_k(float* __restrict__ mem, const float* __restrict__ w3,
    const float* __restrict__ g, const float* __restrict__ be, u16* __restrict__ memh){
  int row = blockIdx.x;
  int d = threadIdx.x;
  float* mrow = mem + (size_t)row*DM;
  const float* wrow = w3 + (size_t)row*DM;
  float x0 = 0.9f*mrow[d]     + 0.1f*wrow[d];
  float x1 = 0.9f*mrow[d+256] + 0.1f*wrow[d+256];
  float s1 = x0+x1, s2 = x0*x0 + x1*x1;
  s1 = wave_reduce_sum(s1); s2 = wave_reduce_sum(s2);
  __shared__ float r1[4], r2[4];
  int lane = d & 63, w = d>>6;
  if (lane==0){ r1[w]=s1; r2[w]=s2; }
  __syncthreads();
  float S1 = r1[0]+r1[1]+r1[2]+r1[3];
  float S2 = r2[0]+r2[1]+r2[2]+r2[3];
  float mu = S1 * (1.f/DM);
  float var = S2*(1.f/DM) - mu*mu;
  float rs = rsqrtf(var + 1e-5f);
  float y0 = (x0-mu)*rs*g[d] + be[d];
  float y1 = (x1-mu)*rs*g[d+256] + be[d+256];
  mrow[d] = y0; mrow[d+256] = y1;
  memh[(size_t)row*DM + d] = f2b(y0);
  memh[(size_t)row*DM + d+256] = f2b(y1);
}

// ---------------- masked token sum partials (vectorized, per-wave slices) ----------------
__global__ __launch_bounds__(256) void tokpart_k(const u16* __restrict__ tok,
    const int* __restrict__ mask, float* __restrict__ tp){
  int b = blockIdx.x, sl = blockIdx.y;
  int w = threadIdx.x>>6, l = threadIdx.x&63;
  float acc[8] = {};
  #pragma unroll 4
  for (int i=0;i<32;i++){
    int t = sl*128 + w + 4*i;
    float m = (float)mask[b*TT + t];
    s16x8 v = *(const s16x8*)(tok + ((size_t)(b*TT + t))*512 + l*8);
    #pragma unroll
    for (int e=0;e<8;e++) acc[e] += m*b2f((u16)v[e]);
  }
  float* dst = tp + ((size_t)(b*64 + sl*4 + w))*512 + l*8;
  #pragma unroll
  for (int e=0;e<8;e++) dst[e] = acc[e];
}

// ---------------- catden: cat[b][1024] = [tok_sum, ctx], denom[b] ----------------
__global__ __launch_bounds__(256) void catden_k(const float* __restrict__ tp,
    const float* __restrict__ rws, const float* __restrict__ rv,
    const int* __restrict__ mask, float* __restrict__ cat, float* __restrict__ denomv){
  int b = blockIdx.x, tid = threadIdx.x;
  float dn = 0.f;
  for (int t=tid; t<TT; t+=256) dn += (float)mask[b*TT+t];
  dn = wave_reduce_sum(dn);
  __shared__ float dred[4];
  if ((tid&63)==0) dred[tid>>6]=dn;
  #pragma unroll
  for (int it=0; it<2; ++it){
    int d = tid + it*256;
    float ts = 0.f;
    for (int k=0;k<64;k++) ts += tp[((size_t)(b*64+k))*512 + d];
    cat[(size_t)b*1024 + d] = ts;
    float c = 0.f;
    for (int s=0;s<SS;s++) c += rws[b*SS+s]*rv[((size_t)b*SS+s)*DM + d];
    cat[(size_t)b*1024 + 512 + d] = c;
  }
  __syncthreads();
  if (tid==0) denomv[b] = dred[0]+dred[1]+dred[2]+dred[3];
}

// ---------------- fuse: pooled[b][n0..n0+64] ----------------
__global__ __launch_bounds__(256) void fuse_k(const float* __restrict__ cat,
    const float* __restrict__ denomv, const float* __restrict__ fuseW,
    const float* __restrict__ fuseb, float* __restrict__ pooled){
  int b = blockIdx.x, n0 = blockIdx.y*64;
  int l = threadIdx.x&63, kc = threadIdx.x>>6;
  int n = n0 + l;
  float acc = 0.f;
  const float* crow = cat + (size_t)b*1024;
  for (int k=kc*256; k<kc*256+256; ++k)
    acc += crow[k]*fuseW[(size_t)k*512 + n];
  __shared__ float red[4][64];
  red[kc][l] = acc;
  __syncthreads();
  if (kc==0){
    float denom = denomv[b];
    float tot = red[0][l]+red[1][l]+red[2][l]+red[3][l];
    pooled[(size_t)b*512 + n] = (tot + denom*fuseb[n]) / fmaxf(denom, 1.f);
  }
}

// ---------------- cls: out[b][8] ----------------
__global__ __launch_bounds__(256) void cls_k(const float* __restrict__ pooled,
    const float* __restrict__ clsW, const float* __restrict__ clsb, float* __restrict__ out){
  int b = blockIdx.x;
  int c = threadIdx.x&7, kc = threadIdx.x>>3;
  float acc = 0.f;
  const float* prow = pooled + (size_t)b*512;
  for (int d=kc*16; d<kc*16+16; ++d) acc += prow[d]*clsW[d*8+c];
  __shared__ float red[32][8];
  red[kc][c] = acc;
  __syncthreads();
  if (threadIdx.x < 8){
    float tot = 0.f;
    #pragma unroll
    for (int k=0;k<32;k++) tot += red[k][threadIdx.x];
    out[b*8 + threadIdx.x] = tot + clsb[threadIdx.x];
  }
}

extern "C" void kernel_launch(void* const* d_in, const int* in_sizes, int n_in,
                              void* d_out, int out_size, void* d_ws, size_t ws_size,
                              hipStream_t stream){
  (void)in_sizes; (void)n_in; (void)out_size; (void)ws_size;
  const int*   ids   = (const int*)d_in[0];
  const int*   amask = (const int*)d_in[1];
  const float* temb  = (const float*)d_in[2];
  const float* pemb  = (const float*)d_in[3];
  const float* mem0  = (const float*)d_in[4];
  const float* qW=(const float*)d_in[5],  *qB=(const float*)d_in[6];
  const float* kW=(const float*)d_in[7],  *kB=(const float*)d_in[8];
  const float* vW=(const float*)d_in[9],  *vB=(const float*)d_in[10];
  const float* wrW=(const float*)d_in[11],*wrB=(const float*)d_in[12];
  const float* gtW=(const float*)d_in[13],*gtB=(const float*)d_in[14];
  const float* rqW=(const float*)d_in[15],*rqB=(const float*)d_in[16];
  const float* rkW=(const float*)d_in[17],*rkB=(const float*)d_in[18];
  const float* rvW=(const float*)d_in[19],*rvB=(const float*)d_in[20];
  const float* fW=(const float*)d_in[21], *fB=(const float*)d_in[22];
  const float* cW=(const float*)d_in[23], *cB=(const float*)d_in[24];
  const float* tg=(const float*)d_in[25], *tb=(const float*)d_in[26];
  const float* mg=(const float*)d_in[27], *mb=(const float*)d_in[28];

  // ---- workspace layout (~110 MB) ----
  char* p = (char*)d_ws;
  size_t off = 0;
  auto alloc = [&](size_t bytes)->char*{ char* r = p + off; off += (bytes + 255) & ~(size_t)255; return r; };
  u16*   tokens = (u16*)  alloc((size_t)BT*DM*2);        // 67.1 MB
  u16*   Pt     = (u16*)  alloc((size_t)BB*SS*DM*2);     // 2.1 MB
  u16*   BNDT   = (u16*)  alloc((size_t)BB*SS*TT*2);     // 8.4 MB
  float* cspart = (float*)alloc((size_t)BB*32*64*4);     // 0.26 MB
  float* wtpart = (float*)alloc((size_t)4*2048*512*4);   // 16.8 MB (hosts aliases below)
  u16*   t1h    = (u16*)  alloc((size_t)2048*512*2);
  u16*   t2h    = (u16*)  alloc((size_t)2048*512*2);
  u16*   zh     = (u16*)  alloc((size_t)2048*512*2);
  float* mem    = (float*)alloc((size_t)BB*SS*DM*4);
  u16*   memh   = (u16*)  alloc((size_t)BB*SS*DM*2);
  u16*   vWT    = (u16*)  alloc(512*512*2);
  u16*   wrWT   = (u16*)  alloc(512*512*2);
  u16*   gtWT   = (u16*)  alloc(512*512*2);
  u16*   rvWT   = (u16*)  alloc(512*512*2);
  u16*   WqkT   = (u16*)  alloc(512*512*2);
  u16*   WqkT_r = (u16*)  alloc(512*512*2);
  float* bq     = (float*)alloc(512*4);
  float* bq_r   = (float*)alloc(512*4);
  float* wcb    = (float*)alloc(512*4);
  float* wcb_r  = (float*)alloc(512*4);
  float* cb0s   = (float*)alloc(256);
  float* cbuf   = (float*)alloc(2048*4);
  float* slot   = (float*)alloc(2048*4);
  float* rr     = (float*)alloc(2048*4);
  float* raw    = (float*)alloc(2048*4);
  float* catbuf = (float*)alloc((size_t)BB*1024*4);
  float* denomv = (float*)alloc(BB*4);
  float* pooled = (float*)alloc((size_t)BB*512*4);
  // aliases inside wtpart (liveness-disjoint):
  float* rv32   = wtpart;                       // read phase only (4 MB)
  float* tspart = wtpart + 1048576;             // read phase only (4 MB: 32*64*512)
  float* gh32   = wtpart + 2097152;             // after wtred, before next wt (4 MB)
  u16*   qWb    = (u16*)((char*)wtpart + 12582912);  // precompute only
  u16*   kWb    = qWb + 512*512;
  u16*   rqWb   = kWb + 512*512;
  u16*   rkWb   = rqWb + 512*512;

  // ---- precompute ----
  conv_k<<<1024, 256, 0, stream>>>(qW, qWb);
  conv_k<<<1024, 256, 0, stream>>>(kW, kWb);
  conv_k<<<1024, 256, 0, stream>>>(rqW, rqWb);
  conv_k<<<1024, 256, 0, stream>>>(rkW, rkWb);
  tconv_k<<<dim3(16,16), 256, 0, stream>>>(vW, vWT);
  tconv_k<<<dim3(16,16), 256, 0, stream>>>(wrW, wrWT);
  tconv_k<<<dim3(16,16), 256, 0, stream>>>(gtW, gtWT);
  tconv_k<<<dim3(16,16), 256, 0, stream>>>(rvW, rvWT);
  ntgemm_k<4><<<dim3(16,8), 128, 0, stream>>>(qWb, kWb, nullptr, nullptr, nullptr, WqkT, SCALE);
  ntgemm_k<4><<<dim3(16,8), 128, 0, stream>>>(rqWb, rkWb, nullptr, nullptr, nullptr, WqkT_r, SCALE);
  matvec_k<<<128, 256, 0, stream>>>(qW, kB, bq);
  matvec_k<<<128, 256, 0, stream>>>(rqW, rkB, bq_r);
  matvec_k<<<128, 256, 0, stream>>>(kW, qB, wcb);
  matvec_k<<<128, 256, 0, stream>>>(rkW, rqB, wcb_r);
  dot2_k<<<1, 128, 0, stream>>>(kB, qB, rkB, rqB, cb0s);
  embed_ln_k<<<BT, 256, 0, stream>>>(ids, temb, pemb, tg, tb, tokens);
  meminit_k<<<(BB*SS*DM)/256, 256, 0, stream>>>(mem0, mem, memh);

  // ---- recurrent steps ----
  for (int step=0; step<NSTEPS; ++step){
    ntgemm_k<0><<<dim3(64,8), 128, 0, stream>>>(memh, WqkT, bq, nullptr, nullptr, Pt, 0.f);
    cb_k<<<512, 256, 0, stream>>>(mem, wcb, cb0s, cbuf);
    bind_k<<<dim3(32,32), 64, 0, stream>>>(tokens, Pt, cbuf, amask, BNDT, cspart);
    csred_k<<<32, 64, 0, stream>>>(cspart, slot, rr, raw);
    wt_k<<<dim3(4,32,4), 256, 0, stream>>>(BNDT, tokens, wtpart);
    wtred_k<<<4096, 256, 0, stream>>>(wtpart, slot, t1h);
    ntgemm_k<1><<<dim3(64,8), 128, 0, stream>>>(t1h, vWT, vB, nullptr, rr, t2h, 0.f);
    ntgemm_k<0><<<dim3(64,8), 128, 0, stream>>>(t2h, wrWT, wrB, nullptr, nullptr, zh, 0.f);
    ntgemm_k<2><<<dim3(64,8), 128, 0, stream>>>(zh, gtWT, gtB, zh, nullptr, gh32, 0.f);
    mem_ln_k<<<BB*SS, 256, 0, stream>>>(mem, gh32, mg, mb, memh);
  }

  // ---- read phase ----
  ntgemm_k<0><<<dim3(64,8), 128, 0, stream>>>(memh, WqkT_r, bq_r, nullptr, nullptr, Pt, 0.f);
  cb_k<<<512, 256, 0, stream>>>(mem, wcb_r, cb0s+1, cbuf);
  bind_k<<<dim3(32,32), 64, 0, stream>>>(tokens, Pt, cbuf, amask, BNDT, cspart);
  csred_k<<<32, 64, 0, stream>>>(cspart, slot, rr, raw);
  ntgemm_k<3><<<dim3(64,8), 128, 0, stream>>>(memh, rvWT, rvB, nullptr, nullptr, rv32, 0.f);
  tokpart_k<<<dim3(32,16), 256, 0, stream>>>(tokens, amask, tspart);
  catden_k<<<32, 256, 0, stream>>>(tspart, raw, rv32, amask, catbuf, denomv);
  fuse_k<<<dim3(32,8), 256, 0, stream>>>(catbuf, denomv, fW, fB, pooled);
  cls_k<<<32, 256, 0, stream>>>(pooled, cW, cB, (float*)d_out);
}

// Round 8
// 586.054 us; speedup vs baseline: 4.6568x; 1.0639x over previous
//
#include <hip/hip_runtime.h>
#include <hip/hip_bf16.h>
#include <math.h>

#define BB 32
#define TT 2048
#define DM 512
#define SS 64
#define BT (BB*TT)
#define NSTEPS 4
#define SCALE 0.044194173824159216f

typedef unsigned short u16;
typedef unsigned int u32;
typedef __attribute__((ext_vector_type(8))) short s16x8;
typedef __attribute__((ext_vector_type(4))) float f32x4;
typedef __attribute__((ext_vector_type(4))) unsigned u32x4;

__device__ __forceinline__ u16 f2b(float x){
  __hip_bfloat16 h = __float2bfloat16(x);
  return *reinterpret_cast<u16*>(&h);
}
__device__ __forceinline__ float b2f(u16 u){
  __hip_bfloat16 h;
  *reinterpret_cast<u16*>(&h) = u;
  return __bfloat162float(h);
}

static __device__ __forceinline__ float wave_reduce_sum(float v){
  #pragma unroll
  for (int off=32; off; off>>=1) v += __shfl_down(v, off);
  return v;
}

// ---------------- embedding + token LN (bf16 out) ----------------
// wave-per-row: lane l owns elements [8l, 8l+8); pure in-wave xor reductions.
__global__ __launch_bounds__(256) void embed_ln_k(const int* __restrict__ ids,
    const float* __restrict__ temb, const float* __restrict__ pemb,
    const float* __restrict__ g, const float* __restrict__ be, u16* __restrict__ out){
  int row = blockIdx.x*4 + (threadIdx.x>>6);
  int l = threadIdx.x & 63;
  int t = row & (TT-1);
  int id = ids[row];
  const float* te = temb + (size_t)id*DM + l*8;
  const float* pe = pemb + (size_t)t*DM + l*8;
  float4 a0 = *(const float4*)te,     a1 = *(const float4*)(te+4);
  float4 p0 = *(const float4*)pe,     p1 = *(const float4*)(pe+4);
  float x[8] = {a0.x+p0.x, a0.y+p0.y, a0.z+p0.z, a0.w+p0.w,
                a1.x+p1.x, a1.y+p1.y, a1.z+p1.z, a1.w+p1.w};
  float s1 = 0.f, s2 = 0.f;
  #pragma unroll
  for (int e=0;e<8;e++){ s1 += x[e]; s2 += x[e]*x[e]; }
  #pragma unroll
  for (int off=1; off<64; off<<=1){ s1 += __shfl_xor(s1, off); s2 += __shfl_xor(s2, off); }
  float mu = s1*(1.f/DM);
  float var = s2*(1.f/DM) - mu*mu;
  float rs = rsqrtf(var + 1e-5f);
  const float* gp = g + l*8;
  const float* bp = be + l*8;
  float4 g0=*(const float4*)gp, g1=*(const float4*)(gp+4);
  float4 b0=*(const float4*)bp, b1=*(const float4*)(bp+4);
  float gg[8]={g0.x,g0.y,g0.z,g0.w,g1.x,g1.y,g1.z,g1.w};
  float bb[8]={b0.x,b0.y,b0.z,b0.w,b1.x,b1.y,b1.z,b1.w};
  s16x8 o;
  #pragma unroll
  for (int e=0;e<8;e++) o[e] = (short)f2b((x[e]-mu)*rs*gg[e] + bb[e]);
  *(s16x8*)(out + (size_t)row*DM + l*8) = o;
}

// ---------------- generic NT bf16 MFMA gemm: C[M][512] = A[M][512] @ Bm[512][512]^T ----------------
// EPI: 0 = bf16(acc+bias[n]) ; 2 = f32( b2f(mul[m,n]) * sigmoid(acc+bias[n]) ) ;
//      3 = f32(acc+bias[n]) ; 4 = bf16(acc*scalep) ; 5 = bf16(acc + rowv[m]*bias[n] + bias2[n])
template<int EPI>
__global__ __launch_bounds__(128) void ntgemm_k(const u16* __restrict__ A,
    const u16* __restrict__ Bm, const float* __restrict__ bias,
    const u16* __restrict__ mulb, const float* __restrict__ rowv,
    const float* __restrict__ bias2, void* __restrict__ Cout, float scalep){
  int m0 = blockIdx.x*32 + (threadIdx.x>>6)*16;
  int n0 = blockIdx.y*64;
  int l = threadIdx.x & 63;
  int lr = l & 15, lk = (l>>4)*8;
  const u16* Arow = A + (size_t)(m0 + lr)*512 + lk;
  const u16* B0   = Bm + (size_t)(n0 + lr)*512 + lk;
  f32x4 acc[4] = {};
  #pragma unroll
  for (int k0=0;k0<512;k0+=32){
    s16x8 a = *(const s16x8*)(Arow + k0);
    #pragma unroll
    for (int j=0;j<4;j++){
      s16x8 b = *(const s16x8*)(B0 + (size_t)j*16*512 + k0);
      acc[j] = __builtin_amdgcn_mfma_f32_16x16x32_bf16(a, b, acc[j], 0,0,0);
    }
  }
  int mbase = m0 + (l>>4)*4;
  #pragma unroll
  for (int j=0;j<4;j++){
    int n = n0 + j*16 + lr;
    #pragma unroll
    for (int r=0;r<4;r++){
      int m = mbase + r;
      float v = acc[j][r];
      if (EPI==0){ ((u16*)Cout)[(size_t)m*512 + n] = f2b(v + bias[n]); }
      if (EPI==2){
        float z = v + bias[n];
        float sg = 1.f/(1.f + expf(-z));
        ((float*)Cout)[(size_t)m*512 + n] = b2f(mulb[(size_t)m*512 + n]) * sg;
      }
      if (EPI==3){ ((float*)Cout)[(size_t)m*512 + n] = v + bias[n]; }
      if (EPI==4){ ((u16*)Cout)[(size_t)m*512 + n] = f2b(v * scalep); }
      if (EPI==5){ ((u16*)Cout)[(size_t)m*512 + n] = f2b(v + rowv[m]*bias[n] + bias2[n]); }
    }
  }
}

// ---------------- fused scores + top8 softmax binding + colsum partial ----------------
__global__ __launch_bounds__(64) void bind_k(const u16* __restrict__ tok,
    const u16* __restrict__ Pt, const float* __restrict__ cbuf, const int* __restrict__ mask,
    u16* __restrict__ BNDT, float* __restrict__ cspart){
  int b = blockIdx.y, t0 = blockIdx.x*64;
  int l = threadIdx.x;
  int lr = l&15, g = l>>4, lk = g*8;
  __shared__ float sc[64*66];
  __shared__ u16 bt[64*66];

  const u16* Abase = tok + ((size_t)(b*TT + t0 + lr))*512 + lk;
  const u16* Bbase = Pt + ((size_t)(b*SS + lr))*512 + lk;
  f32x4 acc[4][4] = {};
  #pragma unroll
  for (int k0=0;k0<512;k0+=32){
    s16x8 a[4], bb[4];
    #pragma unroll
    for (int mi=0;mi<4;mi++) a[mi] = *(const s16x8*)(Abase + (size_t)mi*16*512 + k0);
    #pragma unroll
    for (int nj=0;nj<4;nj++) bb[nj] = *(const s16x8*)(Bbase + (size_t)nj*16*512 + k0);
    #pragma unroll
    for (int mi=0;mi<4;mi++)
      #pragma unroll
      for (int nj=0;nj<4;nj++)
        acc[mi][nj] = __builtin_amdgcn_mfma_f32_16x16x32_bf16(a[mi], bb[nj], acc[mi][nj], 0,0,0);
  }
  float cbv[4];
  #pragma unroll
  for (int nj=0;nj<4;nj++) cbv[nj] = cbuf[b*SS + 16*nj + lr];
  #pragma unroll
  for (int mi=0;mi<4;mi++)
    #pragma unroll
    for (int nj=0;nj<4;nj++)
      #pragma unroll
      for (int r=0;r<4;r++){
        float x = acc[mi][nj][r] + cbv[nj];
        x = fminf(fmaxf(x, -10.f), 10.f);
        sc[(16*mi + 4*g + r)*66 + 16*nj + lr] = x;
      }

  float sv[64];
  #pragma unroll
  for (int j=0;j<64;j++) sv[j] = sc[l*66 + j];

  u32 work[64];
  #pragma unroll
  for (int j=0;j<64;j++){
    u32 s = __float_as_uint(sv[j]);
    u32 o = s ^ ((u32)(((int)s) >> 31) | 0x80000000u);
    work[j] = (o & 0xFFFFFFC0u) | (u32)(63 - j);
  }
  u32 mtop = 0;
  #pragma unroll
  for (int it=0; it<8; ++it){
    u32 a[32];
    #pragma unroll
    for (int j=0;j<32;j++){ u32 x = work[2*j], y = work[2*j+1]; a[j] = x>y?x:y; }
    #pragma unroll
    for (int lvl=16; lvl>=1; lvl>>=1)
      #pragma unroll
      for (int j=0;j<lvl;j++){ u32 x = a[2*j], y = a[2*j+1]; a[j] = x>y?x:y; }
    u32 m = a[0];
    if (it==0) mtop = m;
    #pragma unroll
    for (int j=0;j<64;j++) work[j] = (work[j]==m) ? 0u : work[j];
  }
  u32 ot = mtop & 0xFFFFFFC0u;
  u32 tb = (ot & 0x80000000u) ? (ot ^ 0x80000000u) : ~ot;
  float T = __uint_as_float(tb);

  float tot = 0.f;
  #pragma unroll
  for (int j=0;j<64;j++){
    float ej = (work[j]==0u) ? expf(sv[j]-T) : 0.f;
    sv[j] = ej;
    tot += ej;
  }
  int mv = mask[b*TT + t0 + l];
  float inv = mv ? 1.f/tot : 0.f;
  #pragma unroll
  for (int j=0;j<64;j++)
    bt[j*66 + l] = f2b(sv[j]*inv);

  const u32* btw = (const u32*)bt;
  u32 rowbuf[32];
  float csum = 0.f;
  #pragma unroll
  for (int w=0;w<32;w++){
    u32 v = btw[l*33 + w];
    rowbuf[w] = v;
    csum += b2f((u16)(v & 0xFFFFu)) + b2f((u16)(v >> 16));
  }
  cspart[((size_t)b*32 + blockIdx.x)*64 + l] = csum;
  u16* dst = BNDT + ((size_t)(b*SS + l))*TT + t0;
  #pragma unroll
  for (int w8=0;w8<8;w8++){
    u32x4 v;
    v[0]=rowbuf[4*w8]; v[1]=rowbuf[4*w8+1]; v[2]=rowbuf[4*w8+2]; v[3]=rowbuf[4*w8+3];
    *(u32x4*)(dst + 8*w8) = v;
  }
}

// ---------------- colsum reduce: slot (clamped), rr, raw ----------------
__global__ __launch_bounds__(64) void csred_k(const float* __restrict__ cspart,
    float* __restrict__ slot, float* __restrict__ rr, float* __restrict__ raw){
  int b = blockIdx.x, s = threadIdx.x;
  float t = 0.f;
  for (int k=0;k<32;k++) t += cspart[((size_t)b*32 + k)*64 + s];
  raw[b*SS+s] = t;
  float sl = fmaxf(t, 1e-6f);
  slot[b*SS+s] = sl;
  rr[b*SS+s] = t/sl;
}

// ---------------- wt: part[ks][b*64+s][d] = sum_{t in slice} BNDT[b,s,t]*tok[b,t,d] ----------------
__global__ __launch_bounds__(256) void wt_k(const u16* __restrict__ BNDT,
    const u16* __restrict__ tok, float* __restrict__ part){
  int dgrp = blockIdx.x, b = blockIdx.y, ks = blockIdx.z;
  int tid = threadIdx.x, w = tid>>6, l = tid&63;
  int lr = l&15, lk = (l>>4)*8;
  __shared__ u16 tk[128][72];
  f32x4 acc[8] = {};
  int trow = tid>>2, dseg = (tid&3)*32;
  const u16* tokbase = tok + ((size_t)b*TT)*512 + dgrp*128;
  const u16* Abase = BNDT + ((size_t)(b*SS + 16*w + lr))*TT;
  for (int chunk=0; chunk<8; ++chunk){
    int tb = ks*512 + chunk*64;
    const u16* src = tokbase + (size_t)(tb + trow)*512 + dseg;
    s16x8 v0 = *(const s16x8*)(src);
    s16x8 v1 = *(const s16x8*)(src+8);
    s16x8 v2 = *(const s16x8*)(src+16);
    s16x8 v3 = *(const s16x8*)(src+24);
    #pragma unroll
    for (int e=0;e<8;e++){
      int d0 = dseg+e, d1 = dseg+8+e, d2 = dseg+16+e, d3 = dseg+24+e;
      tk[d0][(trow + 8*((d0>>5)&3)) & 63] = (u16)v0[e];
      tk[d1][(trow + 8*((d1>>5)&3)) & 63] = (u16)v1[e];
      tk[d2][(trow + 8*((d2>>5)&3)) & 63] = (u16)v2[e];
      tk[d3][(trow + 8*((d3>>5)&3)) & 63] = (u16)v3[e];
    }
    __syncthreads();
    #pragma unroll
    for (int kst=0;kst<2;kst++){
      s16x8 a = *(const s16x8*)(Abase + tb + kst*32 + lk);
      #pragma unroll
      for (int nt=0;nt<8;nt++){
        int dd = nt*16 + lr;
        int cb2 = (kst*32 + lk + 8*((dd>>5)&3)) & 63;
        s16x8 bb = *(const s16x8*)&tk[dd][cb2];
        acc[nt] = __builtin_amdgcn_mfma_f32_16x16x32_bf16(a, bb, acc[nt], 0,0,0);
      }
    }
    __syncthreads();
  }
  float* dst = part + (size_t)ks*2048*512 + ((size_t)(b*SS))*512 + dgrp*128;
  #pragma unroll
  for (int nt=0;nt<8;nt++){
    int d = nt*16 + lr;
    #pragma unroll
    for (int r=0;r<4;r++){
      int s = 16*w + (l>>4)*4 + r;
      dst[(size_t)s*512 + d] = acc[nt][r];
    }
  }
}

// ---------------- wt reduce + /slot -> bf16 ----------------
__global__ __launch_bounds__(256) void wtred_k(const float* __restrict__ part,
    const float* __restrict__ slot, u16* __restrict__ t1h){
  int i = blockIdx.x*256 + threadIdx.x;
  int row = i>>9;
  float v = part[i] + part[i + 2048*512] + part[i + 2*2048*512] + part[i + 3*2048*512];
  t1h[i] = f2b(v / slot[row]);
}

// ---------------- cb[row] = dot(mem[row,:], wcb) + cb0 ----------------
__global__ __launch_bounds__(256) void cb_k(const float* __restrict__ mem,
    const float* __restrict__ wcb, const float* __restrict__ cb0p, float* __restrict__ cb){
  int row = blockIdx.x*4 + (threadIdx.x>>6), l = threadIdx.x&63;
  const float* r = mem + (size_t)row*512;
  float s = 0.f;
  #pragma unroll
  for (int k=0;k<8;k++) s += r[l + 64*k]*wcb[l + 64*k];
  #pragma unroll
  for (int off=32; off; off>>=1) s += __shfl_xor(s, off);
  if (l==0) cb[row] = s + cb0p[0];
}

// ---------------- matvec: out[i] = scale * dot(W[i,:], v) ----------------
__global__ __launch_bounds__(256) void matvec_k(const float* __restrict__ W,
    const float* __restrict__ v, float* __restrict__ out){
  int i = blockIdx.x*4 + (threadIdx.x>>6), l = threadIdx.x&63;
  const float* r = W + (size_t)i*512;
  float s = 0.f;
  #pragma unroll
  for (int k=0;k<8;k++) s += r[l + 64*k]*v[l + 64*k];
  #pragma unroll
  for (int off=32; off; off>>=1) s += __shfl_xor(s, off);
  if (l==0) out[i] = s * SCALE;
}

// ---------------- column matvec: out[n] = sum_o v[o]*W[o,n] ----------------
__global__ __launch_bounds__(256) void matvecc_k(const float* __restrict__ W,
    const float* __restrict__ v, float* __restrict__ out){
  int n = blockIdx.x*256 + threadIdx.x;
  float s = 0.f;
  for (int o=0;o<512;o++) s += v[o]*W[(size_t)o*512 + n];
  out[n] = s;
}

// ---------------- two scaled dots (cb0, cb0_r) ----------------
__global__ __launch_bounds__(128) void dot2_k(const float* __restrict__ a0, const float* __restrict__ b0,
    const float* __restrict__ a1, const float* __restrict__ b1, float* __restrict__ out){
  int w = threadIdx.x>>6, l = threadIdx.x&63;
  const float* a = w ? a1 : a0;
  const float* b = w ? b1 : b0;
  float s = 0.f;
  #pragma unroll
  for (int k=0;k<8;k++) s += a[l + 64*k]*b[l + 64*k];
  #pragma unroll
  for (int off=32; off; off>>=1) s += __shfl_xor(s, off);
  if (l==0) out[w] = s * SCALE;
}

// ---------------- transpose + convert fp32 [512][512] -> bf16 [512][512]^T ----------------
__global__ __launch_bounds__(256) void tconv_k(const float* __restrict__ in, u16* __restrict__ out){
  __shared__ float t[32][33];
  int c0 = blockIdx.x*32, r0 = blockIdx.y*32;
  int cx = threadIdx.x&31, ry = threadIdx.x>>5;
  #pragma unroll
  for (int i=0;i<4;i++){ int r = ry + i*8; t[r][cx] = in[(size_t)(r0+r)*512 + c0+cx]; }
  __syncthreads();
  #pragma unroll
  for (int i=0;i<4;i++){ int r = ry + i*8; out[(size_t)(c0+r)*512 + r0+cx] = f2b(t[cx][r]); }
}

// ---------------- straight cast fp32 -> bf16 ----------------
__global__ __launch_bounds__(256) void conv_k(const float* __restrict__ in, u16* __restrict__ out){
  int i = blockIdx.x*256 + threadIdx.x;
  out[i] = f2b(in[i]);
}

// ---------------- memory init (fp32 + bf16 mirror) ----------------
__global__ __launch_bounds__(256) void meminit_k(const float* __restrict__ src,
    float* __restrict__ mem, u16* __restrict__ memh){
  int i = blockIdx.x*256 + threadIdx.x;
  float v = src[i & (SS*DM-1)];
  mem[i] = v;
  memh[i] = f2b(v);
}

// ---------------- mem = LN(0.9*mem + 0.1*w3) -> fp32 + bf16 mirror ----------------
__global__ __launch_bounds__(256) void mem_ln_k(float* __restrict__ mem, const float* __restrict__ w3,
    const float* __restrict__ g, const float* __restrict__ be, u16* __restrict__ memh){
  int row = blockIdx.x;
  int d = threadIdx.x;
  float* mrow = mem + (size_t)row*DM;
  const float* wrow = w3 + (size_t)row*DM;
  float x0 = 0.9f*mrow[d]     + 0.1f*wrow[d];
  float x1 = 0.9f*mrow[d+256] + 0.1f*wrow[d+256];
  float s1 = x0+x1, s2 = x0*x0 + x1*x1;
  s1 = wave_reduce_sum(s1); s2 = wave_reduce_sum(s2);
  __shared__ float r1[4], r2[4];
  int lane = d & 63, w = d>>6;
  if (lane==0){ r1[w]=s1; r2[w]=s2; }
  __syncthreads();
  float S1 = r1[0]+r1[1]+r1[2]+r1[3];
  float S2 = r2[0]+r2[1]+r2[2]+r2[3];
  float mu = S1 * (1.f/DM);
  float var = S2*(1.f/DM) - mu*mu;
  float rs = rsqrtf(var + 1e-5f);
  float y0 = (x0-mu)*rs*g[d] + be[d];
  float y1 = (x1-mu)*rs*g[d+256] + be[d+256];
  mrow[d] = y0; mrow[d+256] = y1;
  memh[(size_t)row*DM + d] = f2b(y0);
  memh[(size_t)row*DM + d+256] = f2b(y1);
}

// ---------------- masked token sum partials (vectorized, per-wave slices) ----------------
__global__ __launch_bounds__(256) void tokpart_k(const u16* __restrict__ tok,
    const int* __restrict__ mask, float* __restrict__ tp){
  int b = blockIdx.x, sl = blockIdx.y;
  int w = threadIdx.x>>6, l = threadIdx.x&63;
  float acc[8] = {};
  #pragma unroll 4
  for (int i=0;i<32;i++){
    int t = sl*128 + w + 4*i;
    float m = (float)mask[b*TT + t];
    s16x8 v = *(const s16x8*)(tok + ((size_t)(b*TT + t))*512 + l*8);
    #pragma unroll
    for (int e=0;e<8;e++) acc[e] += m*b2f((u16)v[e]);
  }
  float* dst = tp + ((size_t)(b*64 + sl*4 + w))*512 + l*8;
  #pragma unroll
  for (int e=0;e<8;e++) dst[e] = acc[e];
}

// ---------------- catden: cat[b][1024] = [tok_sum, ctx], denom[b] ----------------
__global__ __launch_bounds__(256) void catden_k(const float* __restrict__ tp,
    const float* __restrict__ rws, const float* __restrict__ rv,
    const int* __restrict__ mask, float* __restrict__ cat, float* __restrict__ denomv){
  int b = blockIdx.x, tid = threadIdx.x;
  float dn = 0.f;
  for (int t=tid; t<TT; t+=256) dn += (float)mask[b*TT+t];
  dn = wave_reduce_sum(dn);
  __shared__ float dred[4];
  if ((tid&63)==0) dred[tid>>6]=dn;
  #pragma unroll
  for (int it=0; it<2; ++it){
    int d = tid + it*256;
    float ts = 0.f;
    for (int k=0;k<64;k++) ts += tp[((size_t)(b*64+k))*512 + d];
    cat[(size_t)b*1024 + d] = ts;
    float c = 0.f;
    for (int s=0;s<SS;s++) c += rws[b*SS+s]*rv[((size_t)b*SS+s)*DM + d];
    cat[(size_t)b*1024 + 512 + d] = c;
  }
  __syncthreads();
  if (tid==0) denomv[b] = dred[0]+dred[1]+dred[2]+dred[3];
}

// ---------------- fuse: pooled[b][n0..n0+64] ----------------
__global__ __launch_bounds__(256) void fuse_k(const float* __restrict__ cat,
    const float* __restrict__ denomv, const float* __restrict__ fuseW,
    const float* __restrict__ fuseb, float* __restrict__ pooled){
  int b = blockIdx.x, n0 = blockIdx.y*64;
  int l = threadIdx.x&63, kc = threadIdx.x>>6;
  int n = n0 + l;
  float acc = 0.f;
  const float* crow = cat + (size_t)b*1024;
  for (int k=kc*256; k<kc*256+256; ++k)
    acc += crow[k]*fuseW[(size_t)k*512 + n];
  __shared__ float red[4][64];
  red[kc][l] = acc;
  __syncthreads();
  if (kc==0){
    float denom = denomv[b];
    float tot = red[0][l]+red[1][l]+red[2][l]+red[3][l];
    pooled[(size_t)b*512 + n] = (tot + denom*fuseb[n]) / fmaxf(denom, 1.f);
  }
}

// ---------------- cls: out[b][8] ----------------
__global__ __launch_bounds__(256) void cls_k(const float* __restrict__ pooled,
    const float* __restrict__ clsW, const float* __restrict__ clsb, float* __restrict__ out){
  int b = blockIdx.x;
  int c = threadIdx.x&7, kc = threadIdx.x>>3;
  float acc = 0.f;
  const float* prow = pooled + (size_t)b*512;
  for (int d=kc*16; d<kc*16+16; ++d) acc += prow[d]*clsW[d*8+c];
  __shared__ float red[32][8];
  red[kc][c] = acc;
  __syncthreads();
  if (threadIdx.x < 8){
    float tot = 0.f;
    #pragma unroll
    for (int k=0;k<32;k++) tot += red[k][threadIdx.x];
    out[b*8 + threadIdx.x] = tot + clsb[threadIdx.x];
  }
}

extern "C" void kernel_launch(void* const* d_in, const int* in_sizes, int n_in,
                              void* d_out, int out_size, void* d_ws, size_t ws_size,
                              hipStream_t stream){
  (void)in_sizes; (void)n_in; (void)out_size; (void)ws_size;
  const int*   ids   = (const int*)d_in[0];
  const int*   amask = (const int*)d_in[1];
  const float* temb  = (const float*)d_in[2];
  const float* pemb  = (const float*)d_in[3];
  const float* mem0  = (const float*)d_in[4];
  const float* qW=(const float*)d_in[5],  *qB=(const float*)d_in[6];
  const float* kW=(const float*)d_in[7],  *kB=(const float*)d_in[8];
  const float* vW=(const float*)d_in[9],  *vB=(const float*)d_in[10];
  const float* wrW=(const float*)d_in[11],*wrB=(const float*)d_in[12];
  const float* gtW=(const float*)d_in[13],*gtB=(const float*)d_in[14];
  const float* rqW=(const float*)d_in[15],*rqB=(const float*)d_in[16];
  const float* rkW=(const float*)d_in[17],*rkB=(const float*)d_in[18];
  const float* rvW=(const float*)d_in[19],*rvB=(const float*)d_in[20];
  const float* fW=(const float*)d_in[21], *fB=(const float*)d_in[22];
  const float* cW=(const float*)d_in[23], *cB=(const float*)d_in[24];
  const float* tg=(const float*)d_in[25], *tb=(const float*)d_in[26];
  const float* mg=(const float*)d_in[27], *mb=(const float*)d_in[28];

  // ---- workspace layout (~108 MB) ----
  char* p = (char*)d_ws;
  size_t off = 0;
  auto alloc = [&](size_t bytes)->char*{ char* r = p + off; off += (bytes + 255) & ~(size_t)255; return r; };
  u16*   tokens = (u16*)  alloc((size_t)BT*DM*2);        // 67.1 MB
  u16*   Pt     = (u16*)  alloc((size_t)BB*SS*DM*2);     // 2.1 MB
  u16*   BNDT   = (u16*)  alloc((size_t)BB*SS*TT*2);     // 8.4 MB
  float* cspart = (float*)alloc((size_t)BB*32*64*4);     // 0.26 MB
  float* wtpart = (float*)alloc((size_t)4*2048*512*4);   // 16.8 MB (hosts aliases below)
  u16*   t1h    = (u16*)  alloc((size_t)2048*512*2);
  u16*   zh     = (u16*)  alloc((size_t)2048*512*2);
  float* mem    = (float*)alloc((size_t)BB*SS*DM*4);
  u16*   memh   = (u16*)  alloc((size_t)BB*SS*DM*2);
  u16*   wrWT   = (u16*)  alloc(512*512*2);
  u16*   gtWT   = (u16*)  alloc(512*512*2);
  u16*   rvWT   = (u16*)  alloc(512*512*2);
  u16*   WqkT   = (u16*)  alloc(512*512*2);
  u16*   WqkT_r = (u16*)  alloc(512*512*2);
  u16*   WvwT   = (u16*)  alloc(512*512*2);
  float* bq     = (float*)alloc(512*4);
  float* bq_r   = (float*)alloc(512*4);
  float* wcb    = (float*)alloc(512*4);
  float* wcb_r  = (float*)alloc(512*4);
  float* bvw    = (float*)alloc(512*4);
  float* cb0s   = (float*)alloc(256);
  float* cbuf   = (float*)alloc(2048*4);
  float* slot   = (float*)alloc(2048*4);
  float* rr     = (float*)alloc(2048*4);
  float* raw    = (float*)alloc(2048*4);
  float* catbuf = (float*)alloc((size_t)BB*1024*4);
  float* denomv = (float*)alloc(BB*4);
  float* pooled = (float*)alloc((size_t)BB*512*4);
  // aliases inside wtpart (liveness-disjoint):
  float* rv32   = wtpart;                       // read phase only (4 MB)
  float* tspart = wtpart + 1048576;             // read phase only (4 MB)
  float* gh32   = wtpart + 2097152;             // after wtred, before next wt (4 MB)
  u16*   qWb    = (u16*)((char*)wtpart + 12582912);  // precompute only
  u16*   kWb    = qWb + 512*512;
  u16*   rqWb   = kWb + 512*512;
  u16*   rkWb   = rqWb + 512*512;
  u16*   vWb    = (u16*)((char*)wtpart + 14680064);  // precompute only

  // ---- precompute ----
  conv_k<<<1024, 256, 0, stream>>>(qW, qWb);
  conv_k<<<1024, 256, 0, stream>>>(kW, kWb);
  conv_k<<<1024, 256, 0, stream>>>(rqW, rqWb);
  conv_k<<<1024, 256, 0, stream>>>(rkW, rkWb);
  conv_k<<<1024, 256, 0, stream>>>(vW, vWb);
  tconv_k<<<dim3(16,16), 256, 0, stream>>>(wrW, wrWT);
  tconv_k<<<dim3(16,16), 256, 0, stream>>>(gtW, gtWT);
  tconv_k<<<dim3(16,16), 256, 0, stream>>>(rvW, rvWT);
  ntgemm_k<4><<<dim3(16,8), 128, 0, stream>>>(qWb, kWb, nullptr, nullptr, nullptr, nullptr, WqkT, SCALE);
  ntgemm_k<4><<<dim3(16,8), 128, 0, stream>>>(rqWb, rkWb, nullptr, nullptr, nullptr, nullptr, WqkT_r, SCALE);
  ntgemm_k<4><<<dim3(16,8), 128, 0, stream>>>(wrWT, vWb, nullptr, nullptr, nullptr, nullptr, WvwT, 1.0f);
  matvec_k<<<128, 256, 0, stream>>>(qW, kB, bq);
  matvec_k<<<128, 256, 0, stream>>>(rqW, rkB, bq_r);
  matvec_k<<<128, 256, 0, stream>>>(kW, qB, wcb);
  matvec_k<<<128, 256, 0, stream>>>(rkW, rqB, wcb_r);
  matvecc_k<<<2, 256, 0, stream>>>(wrW, vB, bvw);
  dot2_k<<<1, 128, 0, stream>>>(kB, qB, rkB, rqB, cb0s);
  embed_ln_k<<<BT/4, 256, 0, stream>>>(ids, temb, pemb, tg, tb, tokens);
  meminit_k<<<(BB*SS*DM)/256, 256, 0, stream>>>(mem0, mem, memh);

  // ---- recurrent steps ----
  for (int step=0; step<NSTEPS; ++step){
    ntgemm_k<0><<<dim3(64,8), 128, 0, stream>>>(memh, WqkT, bq, nullptr, nullptr, nullptr, Pt, 0.f);
    cb_k<<<512, 256, 0, stream>>>(mem, wcb, cb0s, cbuf);
    bind_k<<<dim3(32,32), 64, 0, stream>>>(tokens, Pt, cbuf, amask, BNDT, cspart);
    csred_k<<<32, 64, 0, stream>>>(cspart, slot, rr, raw);
    wt_k<<<dim3(4,32,4), 256, 0, stream>>>(BNDT, tokens, wtpart);
    wtred_k<<<4096, 256, 0, stream>>>(wtpart, slot, t1h);
    ntgemm_k<5><<<dim3(64,8), 128, 0, stream>>>(t1h, WvwT, bvw, nullptr, rr, wrB, zh, 0.f);
    ntgemm_k<2><<<dim3(64,8), 128, 0, stream>>>(zh, gtWT, gtB, zh, nullptr, nullptr, gh32, 0.f);
    mem_ln_k<<<BB*SS, 256, 0, stream>>>(mem, gh32, mg, mb, memh);
  }

  // ---- read phase ----
  ntgemm_k<0><<<dim3(64,8), 128, 0, stream>>>(memh, WqkT_r, bq_r, nullptr, nullptr, nullptr, Pt, 0.f);
  cb_k<<<512, 256, 0, stream>>>(mem, wcb_r, cb0s+1, cbuf);
  bind_k<<<dim3(32,32), 64, 0, stream>>>(tokens, Pt, cbuf, amask, BNDT, cspart);
  csred_k<<<32, 64, 0, stream>>>(cspart, slot, rr, raw);
  ntgemm_k<3><<<dim3(64,8), 128, 0, stream>>>(memh, rvWT, rvB, nullptr, nullptr, nullptr, rv32, 0.f);
  tokpart_k<<<dim3(32,16), 256, 0, stream>>>(tokens, amask, tspart);
  catden_k<<<32, 256, 0, stream>>>(tspart, raw, rv32, amask, catbuf, denomv);
  fuse_k<<<dim3(32,8), 256, 0, stream>>>(catbuf, denomv, fW, fB, pooled);
  cls_k<<<32, 256, 0, stream>>>(pooled, cW, cB, (float*)d_out);
}